// Round 5
// baseline (469.969 us; speedup 1.0000x reference)
//
#include <hip/hip_runtime.h>
#include <math.h>

// B=8, T=2048, E=256, H=8, D=32, F=1024
#define TT 2048
#define TE 256
// Q pre-scale: 256^-0.5 * log2(e)  (so softmax exp == exp2 of scores)
#define QSCALE (0.0625f * 1.44269504088896f)

typedef short  bf16x8 __attribute__((ext_vector_type(8)));
typedef float  f32x4  __attribute__((ext_vector_type(4)));
typedef float  f32x16 __attribute__((ext_vector_type(16)));
typedef unsigned short u16x4 __attribute__((ext_vector_type(4)));
typedef unsigned short u16x8 __attribute__((ext_vector_type(8)));

__device__ __forceinline__ unsigned short f2b(float f) {
    union { float f; unsigned int u; } v; v.f = f;
    unsigned int r = v.u + 0x7FFF + ((v.u >> 16) & 1);   // RNE
    return (unsigned short)(r >> 16);
}
__device__ __forceinline__ float b2f(unsigned short u) {
    union { unsigned int i; float f; } v; v.i = ((unsigned int)u) << 16;
    return v.f;
}
__device__ __forceinline__ unsigned int pk_bf16(float a, float b) {
    return (unsigned int)f2b(a) | ((unsigned int)f2b(b) << 16);
}
#define FEXP2(x) exp2f(x)
__device__ __forceinline__ bf16x8 ld8(const unsigned short* p) {
    return *(const bf16x8*)p;
}
#define MFMA16(a, b, c) __builtin_amdgcn_mfma_f32_16x16x32_bf16((a), (b), (c), 0, 0, 0)
#define MFMA32(a, b, c) __builtin_amdgcn_mfma_f32_32x32x16_bf16((a), (b), (c), 0, 0, 0)

// ---------------------------------------------------------------------------
// Weight convert/transpose to bf16 [N][K] row-major
__global__ __launch_bounds__(256) void conv_w(const float* __restrict__ wq,
                                              const float* __restrict__ wk,
                                              const float* __restrict__ wv,
                                              const float* __restrict__ w_lin,
                                              const float* __restrict__ w_f1,
                                              const float* __restrict__ w_f2,
                                              unsigned short* __restrict__ Wqkv,
                                              unsigned short* __restrict__ Wlin,
                                              unsigned short* __restrict__ Wf1,
                                              unsigned short* __restrict__ Wf2) {
    int idx = blockIdx.x * 256 + threadIdx.x;
    if (idx < 196608) {                       // Wqkv_t [768][256]
        int n = idx >> 8, k = idx & 255;
        int which = n >> 8, h = (n >> 5) & 7, d = n & 31;
        const float* w = (which == 0) ? wq : (which == 1) ? wk : wv;
        Wqkv[idx] = f2b(w[(h * 256 + k) * 32 + d]);
    } else if (idx < 262144) {                // Wlin_t [256][256]
        int i = idx - 196608; int n = i >> 8, k = i & 255;
        Wlin[i] = f2b(w_lin[k * 256 + n]);
    } else if (idx < 524288) {                // Wf1_t [1024][256]
        int i = idx - 262144; int n = i >> 8, k = i & 255;
        Wf1[i] = f2b(w_f1[k * 1024 + n]);
    } else {                                  // Wf2_t [256][1024]
        int i = idx - 524288; int n = i >> 10, k = i & 1023;
        Wf2[i] = f2b(w_f2[k * 256 + n]);
    }
}

// ---------------------------------------------------------------------------
// LayerNorm, wave-per-row (E=256 = 64 lanes x float4), shuffle reduce, no LDS
__global__ __launch_bounds__(256) void ln_w(const float* __restrict__ X,
                                            const float* __restrict__ g,
                                            const float* __restrict__ bta,
                                            float* __restrict__ Y,
                                            unsigned short* __restrict__ Yb) {
    int row = blockIdx.x * 4 + (threadIdx.x >> 6);
    int lane = threadIdx.x & 63;
    const float4 v = *(const float4*)&X[(size_t)row * TE + lane * 4];
    float s = v.x + v.y + v.z + v.w;
    float s2 = v.x * v.x + v.y * v.y + v.z * v.z + v.w * v.w;
#pragma unroll
    for (int off = 1; off <= 32; off <<= 1) {
        s  += __shfl_xor(s,  off, 64);
        s2 += __shfl_xor(s2, off, 64);
    }
    float mean = s * (1.0f / TE);
    float var = s2 * (1.0f / TE) - mean * mean;
    float rstd = rsqrtf(var + 1e-5f);
    const float4 gg = *(const float4*)&g[lane * 4];
    const float4 bb = *(const float4*)&bta[lane * 4];
    float4 o;
    o.x = (v.x - mean) * rstd * gg.x + bb.x;
    o.y = (v.y - mean) * rstd * gg.y + bb.y;
    o.z = (v.z - mean) * rstd * gg.z + bb.z;
    o.w = (v.w - mean) * rstd * gg.w + bb.w;
    if (Y) *(float4*)&Y[(size_t)row * TE + lane * 4] = o;
    if (Yb) {
        u16x4 ob = { f2b(o.x), f2b(o.y), f2b(o.z), f2b(o.w) };
        *(u16x4*)&Yb[(size_t)row * TE + lane * 4] = ob;
    }
}

// ---------------------------------------------------------------------------
// bf16 MFMA GEMM: C[M,N] = A[M,K] @ Wt[N,K]^T. Block = 4 waves x 16 m-rows
// (BM=64), BN=64. Small blocks -> big grid -> occupancy hides load latency.
template<int K>
__global__ __launch_bounds__(256) void gemm_t(const unsigned short* __restrict__ A,
                                              const unsigned short* __restrict__ Bt,
                                              const float* __restrict__ bias,
                                              const float* __restrict__ resid,
                                              float* __restrict__ outF,
                                              unsigned short* __restrict__ outB,
                                              int N, int relu) {
    int tid = threadIdx.x;
    int w = tid >> 6, lane = tid & 63, q = lane >> 4, col = lane & 15;
    int m0 = blockIdx.y * 64 + w * 16;
    int n0 = blockIdx.x * 64;
    f32x4 acc[4] = {};
    const unsigned short* ar  = A + (size_t)(m0 + col) * K + q * 8;
    const unsigned short* bp0 = Bt + (size_t)(n0 + col) * K + q * 8;
    const unsigned short* bp1 = bp0 + (size_t)16 * K;
    const unsigned short* bp2 = bp0 + (size_t)32 * K;
    const unsigned short* bp3 = bp0 + (size_t)48 * K;
#pragma unroll 4
    for (int k0 = 0; k0 < K; k0 += 32) {
        bf16x8 a  = ld8(ar + k0);
        bf16x8 b0 = ld8(bp0 + k0), b1 = ld8(bp1 + k0);
        bf16x8 b2 = ld8(bp2 + k0), b3 = ld8(bp3 + k0);
        acc[0] = MFMA16(a, b0, acc[0]);
        acc[1] = MFMA16(a, b1, acc[1]);
        acc[2] = MFMA16(a, b2, acc[2]);
        acc[3] = MFMA16(a, b3, acc[3]);
    }
#pragma unroll
    for (int j = 0; j < 4; ++j) {
        int n = n0 + j * 16 + col;
#pragma unroll
        for (int r = 0; r < 4; ++r) {
            int m = m0 + q * 4 + r;
            float v = acc[j][r];
            if (bias) v += bias[n];
            if (relu) v = fmaxf(v, 0.f);
            if (resid) v += resid[(size_t)m * N + n];
            if (outF) outF[(size_t)m * N + n] = v;
            if (outB) outB[(size_t)m * N + n] = f2b(v);
        }
    }
}

// ---------------------------------------------------------------------------
// QKV GEMM (K=256, BM=64). Epilogue scatter: Qbf (x QSCALE), Kbf in
// [bh][t][32]; V^T (unscaled bf16) in [bh][d][TT] with packed uint2 stores.
__global__ __launch_bounds__(256) void gemm_qkv(const unsigned short* __restrict__ A,
                                                const unsigned short* __restrict__ Bt,
                                                unsigned short* __restrict__ Qbf,
                                                unsigned short* __restrict__ Kbf,
                                                unsigned short* __restrict__ VtRaw) {
    const int K = 256;
    int tid = threadIdx.x;
    int w = tid >> 6, lane = tid & 63, q = lane >> 4, col = lane & 15;
    int m0 = blockIdx.y * 64 + w * 16;
    int n0 = blockIdx.x * 64;
    f32x4 acc[4] = {};
    const unsigned short* ar  = A + (size_t)(m0 + col) * K + q * 8;
    const unsigned short* bp0 = Bt + (size_t)(n0 + col) * K + q * 8;
#pragma unroll 4
    for (int k0 = 0; k0 < K; k0 += 32) {
        bf16x8 a  = ld8(ar + k0);
        bf16x8 b0 = ld8(bp0 + k0), b1 = ld8(bp0 + 16 * K + k0);
        bf16x8 b2 = ld8(bp0 + 32 * K + k0), b3 = ld8(bp0 + 48 * K + k0);
        acc[0] = MFMA16(a, b0, acc[0]);
        acc[1] = MFMA16(a, b1, acc[1]);
        acc[2] = MFMA16(a, b2, acc[2]);
        acc[3] = MFMA16(a, b3, acc[3]);
    }
#pragma unroll
    for (int j = 0; j < 4; ++j) {
        int n = n0 + j * 16 + col;
        int which = n >> 8, h = (n >> 5) & 7, d = n & 31;
        int m = m0 + q * 4;
        int b = m >> 11, t = m & 2047;
        int bh = b * 8 + h;
        if (which == 0) {
#pragma unroll
            for (int r = 0; r < 4; ++r)
                Qbf[((size_t)bh * TT + t + r) * 32 + d] = f2b(acc[j][r] * QSCALE);
        } else if (which == 1) {
#pragma unroll
            for (int r = 0; r < 4; ++r)
                Kbf[((size_t)bh * TT + t + r) * 32 + d] = f2b(acc[j][r]);
        } else {
            uint2 pv;
            pv.x = pk_bf16(acc[j][0], acc[j][1]);
            pv.y = pk_bf16(acc[j][2], acc[j][3]);
            *(uint2*)&VtRaw[((size_t)bh * 32 + d) * TT + t] = pv;
        }
    }
}

// ---------------------------------------------------------------------------
// Pass 1: colLinv[s] = 1 / sum_{t>=s} exp2(q_t . k_s). Balanced: wave u
// handles s-tiles {u, 63-u} (65 t-iterations total for every wave).
__global__ __launch_bounds__(256) void attn_cols(const unsigned short* __restrict__ Qbf,
                                                 const unsigned short* __restrict__ Kbf,
                                                 float* __restrict__ colLinv) {
    int tid = threadIdx.x;
    int w = tid >> 6, lane = tid & 63, hi = lane >> 5, l31 = lane & 31;
    int bh = blockIdx.y;
    int u = blockIdx.x * 4 + w;               // 0..31
    const unsigned short* Qb = Qbf + (size_t)bh * TT * 32;
    const unsigned short* Kb = Kbf + (size_t)bh * TT * 32;
    const f32x16 z16 = {};
#pragma unroll
    for (int phase = 0; phase < 2; ++phase) {
        int stile = phase ? (63 - u) : u;
        int sbase = stile * 32;
        bf16x8 a0 = ld8(Kb + (size_t)(sbase + l31) * 32 + hi * 8);        // d 0..15
        bf16x8 a1 = ld8(Kb + (size_t)(sbase + l31) * 32 + 16 + hi * 8);   // d 16..31
        float acc[16] = {};
        for (int t0 = sbase; t0 < TT; t0 += 32) {
            bf16x8 q0 = ld8(Qb + (size_t)(t0 + l31) * 32 + hi * 8);
            bf16x8 q1 = ld8(Qb + (size_t)(t0 + l31) * 32 + 16 + hi * 8);
            f32x16 st = MFMA32(a0, q0, z16);
            st = MFMA32(a1, q1, st);
            if (t0 == sbase) {
#pragma unroll
                for (int r = 0; r < 16; ++r) {
                    int s_local = (r & 3) + 8 * (r >> 2) + 4 * hi;
                    acc[r] += (l31 >= s_local) ? FEXP2(st[r]) : 0.f;
                }
            } else {
#pragma unroll
                for (int r = 0; r < 16; ++r) acc[r] += FEXP2(st[r]);
            }
        }
#pragma unroll
        for (int off = 1; off <= 16; off <<= 1)
#pragma unroll
            for (int r = 0; r < 16; ++r) acc[r] += __shfl_xor(acc[r], off, 64);
        if (l31 == 0) {
#pragma unroll
            for (int r = 0; r < 16; ++r) {
                int s_local = (r & 3) + 8 * (r >> 2) + 4 * hi;
                colLinv[(size_t)bh * TT + sbase + s_local] = 1.0f / acc[r];
            }
        }
    }
}

// ---------------------------------------------------------------------------
// Vt[bh][d][s] = VtRaw[bh][d][s] * colLinv[bh][s]; one block per (bh,d) row.
__global__ __launch_bounds__(256) void scale_vt(const unsigned short* __restrict__ VtRaw,
                                                const float* __restrict__ colLinv,
                                                unsigned short* __restrict__ Vt) {
    int bhd = blockIdx.x;            // bh*32 + d
    int bh = bhd >> 5;
    int s = threadIdx.x * 8;
    u16x8 v = *(const u16x8*)&VtRaw[(size_t)bhd * TT + s];
    const float4 i0 = *(const float4*)&colLinv[(size_t)bh * TT + s];
    const float4 i1 = *(const float4*)&colLinv[(size_t)bh * TT + s + 4];
    u16x8 o;
    o[0] = f2b(b2f(v[0]) * i0.x); o[1] = f2b(b2f(v[1]) * i0.y);
    o[2] = f2b(b2f(v[2]) * i0.z); o[3] = f2b(b2f(v[3]) * i0.w);
    o[4] = f2b(b2f(v[4]) * i1.x); o[5] = f2b(b2f(v[5]) * i1.y);
    o[6] = f2b(b2f(v[6]) * i1.z); o[7] = f2b(b2f(v[7]) * i1.w);
    *(u16x8*)&Vt[(size_t)bhd * TT + s] = o;
}

// ---------------------------------------------------------------------------
// Pass 2: O[t,:] = sum_{s<=t} exp2(q_t.k_s) * V'[s,:], xh = bf16(xn + O).
// Balanced: wave u handles t-tiles {u, 63-u} (65 chunks total per wave).
// Wave-private Pt (stride 36 ushorts: 72B rows -> <=2-way banks, 8B aligned),
// P read back as 2x b64. K/V prefetched one chunk ahead. No __syncthreads.
__global__ __launch_bounds__(256) void attn_out(const unsigned short* __restrict__ Qbf,
                                                const unsigned short* __restrict__ Kbf,
                                                const unsigned short* __restrict__ Vt,
                                                const float* __restrict__ xn,
                                                unsigned short* __restrict__ xh_bf) {
    __shared__ unsigned short Pt[128][36];
    int tid = threadIdx.x;
    int w = tid >> 6, lane = tid & 63, q = lane >> 4, col = lane & 15;
    int bh = blockIdx.y, b = bh >> 3, h = bh & 7;
    int u = blockIdx.x * 4 + w;               // 0..31
    int trow = w * 32;
    const unsigned short* Kb = Kbf + (size_t)bh * TT * 32;
    const unsigned short* Vb = Vt + (size_t)bh * 32 * TT;
    const f32x4 z = {};

#pragma unroll
    for (int phase = 0; phase < 2; ++phase) {
        int tt = phase ? (63 - u) : u;
        int tbase = tt * 32;
        const unsigned short* Qrow = Qbf + ((size_t)bh * TT + tbase) * 32;
        bf16x8 q0 = ld8(Qrow + (size_t)col * 32 + q * 8);          // t 0..15
        bf16x8 q1 = ld8(Qrow + (size_t)(16 + col) * 32 + q * 8);   // t 16..31
        f32x4 o00 = z, o01 = z, o10 = z, o11 = z;   // [tsub][dsub]

        bf16x8 ck0 = ld8(Kb + (size_t)col * 32 + q * 8);          // s 0..15
        bf16x8 ck1 = ld8(Kb + (size_t)(16 + col) * 32 + q * 8);   // s 16..31
        bf16x8 cv0 = ld8(Vb + (size_t)col * TT + q * 8);          // d 0..15
        bf16x8 cv1 = ld8(Vb + (size_t)(16 + col) * TT + q * 8);   // d 16..31

        for (int s0 = 0; s0 <= tbase; s0 += 32) {
            bool diag = (s0 == tbase);
            // S^T tiles: C-layout col=t_local, row=q*4+r=s_local
            f32x4 st00 = MFMA16(ck0, q0, z);
            f32x4 st01 = MFMA16(ck0, q1, z);
            f32x4 st11 = MFMA16(ck1, q1, z);
            f32x4 st10 = diag ? z : MFMA16(ck1, q0, z);
            // prefetch next chunk
            int sn = s0 + 32;
            if (sn <= tbase) {
                ck0 = ld8(Kb + (size_t)(sn + col) * 32 + q * 8);
                ck1 = ld8(Kb + (size_t)(sn + 16 + col) * 32 + q * 8);
            }
            uint2 w0, w1, w2, w3;
            if (diag) {   // mask s_g <= t_g
                float e0[4], e1[4], e3[4];
#pragma unroll
                for (int r = 0; r < 4; ++r) {
                    int sl = q * 4 + r;
                    e0[r] = (sl <= col) ? FEXP2(st00[r]) : 0.f;
                    e1[r] = FEXP2(st01[r]);              // s<16<=t: full
                    e3[r] = (sl <= col) ? FEXP2(st11[r]) : 0.f;
                }
                w0.x = pk_bf16(e0[0], e0[1]); w0.y = pk_bf16(e0[2], e0[3]);
                w1.x = pk_bf16(e1[0], e1[1]); w1.y = pk_bf16(e1[2], e1[3]);
                w2.x = 0u;                    w2.y = 0u;
                w3.x = pk_bf16(e3[0], e3[1]); w3.y = pk_bf16(e3[2], e3[3]);
            } else {
                w0.x = pk_bf16(FEXP2(st00[0]), FEXP2(st00[1]));
                w0.y = pk_bf16(FEXP2(st00[2]), FEXP2(st00[3]));
                w1.x = pk_bf16(FEXP2(st01[0]), FEXP2(st01[1]));
                w1.y = pk_bf16(FEXP2(st01[2]), FEXP2(st01[3]));
                w2.x = pk_bf16(FEXP2(st10[0]), FEXP2(st10[1]));
                w2.y = pk_bf16(FEXP2(st10[2]), FEXP2(st10[3]));
                w3.x = pk_bf16(FEXP2(st11[0]), FEXP2(st11[1]));
                w3.y = pk_bf16(FEXP2(st11[2]), FEXP2(st11[3]));
            }
            *(uint2*)&Pt[trow + col][q * 4]           = w0;
            *(uint2*)&Pt[trow + 16 + col][q * 4]      = w1;
            *(uint2*)&Pt[trow + col][16 + q * 4]      = w2;
            *(uint2*)&Pt[trow + 16 + col][16 + q * 4] = w3;
            // P A-frags: two 8B reads each (rows are 8B aligned at stride 36)
            union { uint2 u2[2]; bf16x8 v; } p0u, p1u;
            p0u.u2[0] = *(const uint2*)&Pt[trow + col][q * 8];
            p0u.u2[1] = *(const uint2*)&Pt[trow + col][q * 8 + 4];
            p1u.u2[0] = *(const uint2*)&Pt[trow + 16 + col][q * 8];
            p1u.u2[1] = *(const uint2*)&Pt[trow + 16 + col][q * 8 + 4];
            // PV
            o00 = MFMA16(p0u.v, cv0, o00);
            o01 = MFMA16(p0u.v, cv1, o01);
            o10 = MFMA16(p1u.v, cv0, o10);
            o11 = MFMA16(p1u.v, cv1, o11);
            if (sn <= tbase) {
                cv0 = ld8(Vb + (size_t)col * TT + sn + q * 8);
                cv1 = ld8(Vb + (size_t)(16 + col) * TT + sn + q * 8);
            }
        }

        // Epilogue: C-layout col=d_local, row=q*4+r=t_local; xh = xn + O
#pragma unroll
        for (int r = 0; r < 4; ++r) {
            int t0g = tbase + q * 4 + r;
            int t1g = tbase + 16 + q * 4 + r;
            size_t i00 = ((size_t)(b * TT) + t0g) * TE + h * 32 + col;
            size_t i10 = ((size_t)(b * TT) + t1g) * TE + h * 32 + col;
            xh_bf[i00]      = f2b(o00[r] + xn[i00]);
            xh_bf[i00 + 16] = f2b(o01[r] + xn[i00 + 16]);
            xh_bf[i10]      = f2b(o10[r] + xn[i10]);
            xh_bf[i10 + 16] = f2b(o11[r] + xn[i10 + 16]);
        }
    }
}

// ---------------------------------------------------------------------------
extern "C" void kernel_launch(void* const* d_in, const int* in_sizes, int n_in,
                              void* d_out, int out_size, void* d_ws, size_t ws_size,
                              hipStream_t stream) {
    (void)in_sizes; (void)n_in; (void)out_size; (void)ws_size;
    const float* x     = (const float*)d_in[0];
    const float* wq    = (const float*)d_in[1];
    const float* wk    = (const float*)d_in[2];
    const float* wv    = (const float*)d_in[3];
    const float* w_lin = (const float*)d_in[4];
    const float* b_lin = (const float*)d_in[5];
    const float* g1    = (const float*)d_in[6];
    const float* beta1 = (const float*)d_in[7];
    const float* g2    = (const float*)d_in[8];
    const float* beta2 = (const float*)d_in[9];
    const float* w_f1  = (const float*)d_in[10];
    const float* b_f1  = (const float*)d_in[11];
    const float* w_f2  = (const float*)d_in[12];
    const float* b_f2  = (const float*)d_in[13];
    float* out = (float*)d_out;

    char* ws = (char*)d_ws;
    unsigned short* Wqkv_t = (unsigned short*)(ws + 0);         //  384 KB
    unsigned short* Wlin_t = (unsigned short*)(ws + 393216);    //  128 KB
    unsigned short* Wf1_t  = (unsigned short*)(ws + 524288);    //  512 KB
    unsigned short* Wf2_t  = (unsigned short*)(ws + 1048576);   //  512 KB
    float*          xn     = (float*)(ws + 1572864);            //   16 MB  [xl aliases]
    unsigned short* xn_bf  = (unsigned short*)(ws + 18350080);  //    8 MB  [x2_bf aliases]
    unsigned short* Qbf    = (unsigned short*)(ws + 26738688);  //    8 MB ┐
    unsigned short* Kbf    = (unsigned short*)(ws + 35127296);  //    8 MB ├ h_bf aliases (32 MB)
    unsigned short* VtRaw  = (unsigned short*)(ws + 43515904);  //    8 MB │
    unsigned short* Vt     = (unsigned short*)(ws + 51904512);  //    8 MB ┘
    unsigned short* xh_bf  = (unsigned short*)(ws + 60293120);  //    8 MB
    float*          x2     = (float*)(ws + 68681728);           //   16 MB
    float*          colLinv= (float*)(ws + 85459072);           //  512 KB
    float*          xl     = xn;
    unsigned short* x2_bf  = xn_bf;
    unsigned short* h_bf   = Qbf;

    conv_w<<<3072, 256, 0, stream>>>(wq, wk, wv, w_lin, w_f1, w_f2,
                                     Wqkv_t, Wlin_t, Wf1_t, Wf2_t);
    ln_w<<<4096, 256, 0, stream>>>(x, g1, beta1, xn, xn_bf);
    gemm_qkv<<<dim3(12, 256), 256, 0, stream>>>(xn_bf, Wqkv_t, Qbf, Kbf, VtRaw);
    attn_cols<<<dim3(8, 64), 256, 0, stream>>>(Qbf, Kbf, colLinv);
    scale_vt<<<2048, 256, 0, stream>>>(VtRaw, colLinv, Vt);
    attn_out<<<dim3(8, 64), 256, 0, stream>>>(Qbf, Kbf, Vt, xn, xh_bf);
    gemm_t<256><<<dim3(4, 256), 256, 0, stream>>>(xh_bf, Wlin_t, b_lin, nullptr,
                                                  xl, nullptr, 256, 0);
    ln_w<<<4096, 256, 0, stream>>>(xl, g2, beta2, x2, x2_bf);
    gemm_t<256><<<dim3(16, 256), 256, 0, stream>>>(x2_bf, Wf1_t, b_f1, nullptr,
                                                   nullptr, h_bf, 1024, 1);
    gemm_t<1024><<<dim3(4, 256), 256, 0, stream>>>(h_bf, Wf2_t, b_f2, x2,
                                                   out, nullptr, 256, 0);
}

// Round 6
// 382.392 us; speedup vs baseline: 1.2290x; 1.2290x over previous
//
#include <hip/hip_runtime.h>
#include <math.h>

// B=8, T=2048, E=256, H=8, D=32, F=1024
#define TT 2048
#define TE 256
// Q pre-scale: 256^-0.5 * log2(e)  (so softmax exp == exp2 of scores)
#define QSCALE (0.0625f * 1.44269504088896f)

typedef short  bf16x8 __attribute__((ext_vector_type(8)));
typedef float  f32x4  __attribute__((ext_vector_type(4)));
typedef float  f32x16 __attribute__((ext_vector_type(16)));
typedef unsigned short u16x4 __attribute__((ext_vector_type(4)));
typedef unsigned short u16x8 __attribute__((ext_vector_type(8)));

__device__ __forceinline__ unsigned short f2b(float f) {
    union { float f; unsigned int u; } v; v.f = f;
    unsigned int r = v.u + 0x7FFF + ((v.u >> 16) & 1);   // RNE
    return (unsigned short)(r >> 16);
}
__device__ __forceinline__ float b2f(unsigned short u) {
    union { unsigned int i; float f; } v; v.i = ((unsigned int)u) << 16;
    return v.f;
}
__device__ __forceinline__ unsigned int pk_bf16(float a, float b) {
    return (unsigned int)f2b(a) | ((unsigned int)f2b(b) << 16);
}
#define FEXP2(x) exp2f(x)
__device__ __forceinline__ bf16x8 ld8(const unsigned short* p) {
    return *(const bf16x8*)p;
}
#define MFMA16(a, b, c) __builtin_amdgcn_mfma_f32_16x16x32_bf16((a), (b), (c), 0, 0, 0)
#define MFMA32(a, b, c) __builtin_amdgcn_mfma_f32_32x32x16_bf16((a), (b), (c), 0, 0, 0)

// ---------------------------------------------------------------------------
// Weight convert/transpose to bf16 [N][K] row-major
__global__ __launch_bounds__(256) void conv_w(const float* __restrict__ wq,
                                              const float* __restrict__ wk,
                                              const float* __restrict__ wv,
                                              const float* __restrict__ w_lin,
                                              const float* __restrict__ w_f1,
                                              const float* __restrict__ w_f2,
                                              unsigned short* __restrict__ Wqkv,
                                              unsigned short* __restrict__ Wlin,
                                              unsigned short* __restrict__ Wf1,
                                              unsigned short* __restrict__ Wf2) {
    int idx = blockIdx.x * 256 + threadIdx.x;
    if (idx < 196608) {                       // Wqkv_t [768][256]
        int n = idx >> 8, k = idx & 255;
        int which = n >> 8, h = (n >> 5) & 7, d = n & 31;
        const float* w = (which == 0) ? wq : (which == 1) ? wk : wv;
        Wqkv[idx] = f2b(w[(h * 256 + k) * 32 + d]);
    } else if (idx < 262144) {                // Wlin_t [256][256]
        int i = idx - 196608; int n = i >> 8, k = i & 255;
        Wlin[i] = f2b(w_lin[k * 256 + n]);
    } else if (idx < 524288) {                // Wf1_t [1024][256]
        int i = idx - 262144; int n = i >> 8, k = i & 255;
        Wf1[i] = f2b(w_f1[k * 1024 + n]);
    } else {                                  // Wf2_t [256][1024]
        int i = idx - 524288; int n = i >> 10, k = i & 1023;
        Wf2[i] = f2b(w_f2[k * 256 + n]);
    }
}

// ---------------------------------------------------------------------------
// LayerNorm, wave-per-row (E=256 = 64 lanes x float4), shuffle reduce, no LDS
__global__ __launch_bounds__(256) void ln_w(const float* __restrict__ X,
                                            const float* __restrict__ g,
                                            const float* __restrict__ bta,
                                            float* __restrict__ Y,
                                            unsigned short* __restrict__ Yb) {
    int row = blockIdx.x * 4 + (threadIdx.x >> 6);
    int lane = threadIdx.x & 63;
    const float4 v = *(const float4*)&X[(size_t)row * TE + lane * 4];
    float s = v.x + v.y + v.z + v.w;
    float s2 = v.x * v.x + v.y * v.y + v.z * v.z + v.w * v.w;
#pragma unroll
    for (int off = 1; off <= 32; off <<= 1) {
        s  += __shfl_xor(s,  off, 64);
        s2 += __shfl_xor(s2, off, 64);
    }
    float mean = s * (1.0f / TE);
    float var = s2 * (1.0f / TE) - mean * mean;
    float rstd = rsqrtf(var + 1e-5f);
    const float4 gg = *(const float4*)&g[lane * 4];
    const float4 bb = *(const float4*)&bta[lane * 4];
    float4 o;
    o.x = (v.x - mean) * rstd * gg.x + bb.x;
    o.y = (v.y - mean) * rstd * gg.y + bb.y;
    o.z = (v.z - mean) * rstd * gg.z + bb.z;
    o.w = (v.w - mean) * rstd * gg.w + bb.w;
    if (Y) *(float4*)&Y[(size_t)row * TE + lane * 4] = o;
    if (Yb) {
        u16x4 ob = { f2b(o.x), f2b(o.y), f2b(o.z), f2b(o.w) };
        *(u16x4*)&Yb[(size_t)row * TE + lane * 4] = ob;
    }
}

// ---------------------------------------------------------------------------
// bf16 MFMA GEMM: C[M,N] = A[M,K] @ Wt[N,K]^T.
// Wave tile 64m x 64n (16 MFMA per 8 loads); block = 2x2 waves = 128x128.
template<int K>
__global__ __launch_bounds__(256, 2) void gemm64(const unsigned short* __restrict__ A,
                                                 const unsigned short* __restrict__ Bt,
                                                 const float* __restrict__ bias,
                                                 const float* __restrict__ resid,
                                                 float* __restrict__ outF,
                                                 unsigned short* __restrict__ outB,
                                                 int N, int relu) {
    int tid = threadIdx.x;
    int w = tid >> 6, lane = tid & 63, q = lane >> 4, col = lane & 15;
    int wm = w & 1, wn = w >> 1;
    int m0 = blockIdx.y * 128 + wm * 64;
    int n0 = blockIdx.x * 128 + wn * 64;
    f32x4 acc[4][4] = {};
    const unsigned short* ar = A + (size_t)(m0 + col) * K + q * 8;
    const unsigned short* bp = Bt + (size_t)(n0 + col) * K + q * 8;
#pragma unroll 2
    for (int k0 = 0; k0 < K; k0 += 32) {
        bf16x8 a[4], b[4];
#pragma unroll
        for (int i = 0; i < 4; ++i) a[i] = ld8(ar + (size_t)(i * 16) * K + k0);
#pragma unroll
        for (int j = 0; j < 4; ++j) b[j] = ld8(bp + (size_t)(j * 16) * K + k0);
#pragma unroll
        for (int i = 0; i < 4; ++i)
#pragma unroll
            for (int j = 0; j < 4; ++j)
                acc[i][j] = MFMA16(a[i], b[j], acc[i][j]);
    }
#pragma unroll
    for (int i = 0; i < 4; ++i)
#pragma unroll
    for (int j = 0; j < 4; ++j) {
        int n = n0 + j * 16 + col;
#pragma unroll
        for (int r = 0; r < 4; ++r) {
            int m = m0 + i * 16 + q * 4 + r;
            float v = acc[i][j][r];
            if (bias) v += bias[n];
            if (relu) v = fmaxf(v, 0.f);
            if (resid) v += resid[(size_t)m * N + n];
            if (outF) outF[(size_t)m * N + n] = v;
            if (outB) outB[(size_t)m * N + n] = f2b(v);
        }
    }
}

// ---------------------------------------------------------------------------
// QKV GEMM (K=256), wave tile 64x64. Epilogue scatter: Qbf (x QSCALE), Kbf in
// [bh][t][32]; V^T (unscaled bf16) in [bh][d][TT] with packed uint2 stores.
__global__ __launch_bounds__(256, 2) void gemm_qkv(const unsigned short* __restrict__ A,
                                                   const unsigned short* __restrict__ Bt,
                                                   unsigned short* __restrict__ Qbf,
                                                   unsigned short* __restrict__ Kbf,
                                                   unsigned short* __restrict__ VtRaw) {
    const int K = 256;
    int tid = threadIdx.x;
    int w = tid >> 6, lane = tid & 63, q = lane >> 4, col = lane & 15;
    int wm = w & 1, wn = w >> 1;
    int m0 = blockIdx.y * 128 + wm * 64;
    int n0 = blockIdx.x * 128 + wn * 64;
    f32x4 acc[4][4] = {};
    const unsigned short* ar = A + (size_t)(m0 + col) * K + q * 8;
    const unsigned short* bp = Bt + (size_t)(n0 + col) * K + q * 8;
#pragma unroll 2
    for (int k0 = 0; k0 < K; k0 += 32) {
        bf16x8 a[4], b[4];
#pragma unroll
        for (int i = 0; i < 4; ++i) a[i] = ld8(ar + (size_t)(i * 16) * K + k0);
#pragma unroll
        for (int j = 0; j < 4; ++j) b[j] = ld8(bp + (size_t)(j * 16) * K + k0);
#pragma unroll
        for (int i = 0; i < 4; ++i)
#pragma unroll
            for (int j = 0; j < 4; ++j)
                acc[i][j] = MFMA16(a[i], b[j], acc[i][j]);
    }
#pragma unroll
    for (int i = 0; i < 4; ++i)
#pragma unroll
    for (int j = 0; j < 4; ++j) {
        int n = n0 + j * 16 + col;
        int which = n >> 8, h = (n >> 5) & 7, d = n & 31;
        int m = m0 + i * 16 + q * 4;
        int b = m >> 11, t = m & 2047;
        int bh = b * 8 + h;
        if (which == 0) {
#pragma unroll
            for (int r = 0; r < 4; ++r)
                Qbf[((size_t)bh * TT + t + r) * 32 + d] = f2b(acc[i][j][r] * QSCALE);
        } else if (which == 1) {
#pragma unroll
            for (int r = 0; r < 4; ++r)
                Kbf[((size_t)bh * TT + t + r) * 32 + d] = f2b(acc[i][j][r]);
        } else {
            uint2 pv;
            pv.x = pk_bf16(acc[i][j][0], acc[i][j][1]);
            pv.y = pk_bf16(acc[i][j][2], acc[i][j][3]);
            *(uint2*)&VtRaw[((size_t)bh * 32 + d) * TT + t] = pv;
        }
    }
}

// ---------------------------------------------------------------------------
// Pass 1: colLinv[s] = 1 / sum_{t>=s} exp2(q_t . k_s). Balanced: wave u
// handles s-tiles {u, 63-u} (65 t-iterations total for every wave).
__global__ __launch_bounds__(256) void attn_cols(const unsigned short* __restrict__ Qbf,
                                                 const unsigned short* __restrict__ Kbf,
                                                 float* __restrict__ colLinv) {
    int tid = threadIdx.x;
    int w = tid >> 6, lane = tid & 63, hi = lane >> 5, l31 = lane & 31;
    int bh = blockIdx.y;
    int u = blockIdx.x * 4 + w;               // 0..31
    const unsigned short* Qb = Qbf + (size_t)bh * TT * 32;
    const unsigned short* Kb = Kbf + (size_t)bh * TT * 32;
    const f32x16 z16 = {};
#pragma unroll
    for (int phase = 0; phase < 2; ++phase) {
        int stile = phase ? (63 - u) : u;
        int sbase = stile * 32;
        bf16x8 a0 = ld8(Kb + (size_t)(sbase + l31) * 32 + hi * 8);        // d 0..15
        bf16x8 a1 = ld8(Kb + (size_t)(sbase + l31) * 32 + 16 + hi * 8);   // d 16..31
        float acc[16] = {};
        for (int t0 = sbase; t0 < TT; t0 += 32) {
            bf16x8 q0 = ld8(Qb + (size_t)(t0 + l31) * 32 + hi * 8);
            bf16x8 q1 = ld8(Qb + (size_t)(t0 + l31) * 32 + 16 + hi * 8);
            f32x16 st = MFMA32(a0, q0, z16);
            st = MFMA32(a1, q1, st);
            if (t0 == sbase) {
#pragma unroll
                for (int r = 0; r < 16; ++r) {
                    int s_local = (r & 3) + 8 * (r >> 2) + 4 * hi;
                    acc[r] += (l31 >= s_local) ? FEXP2(st[r]) : 0.f;
                }
            } else {
#pragma unroll
                for (int r = 0; r < 16; ++r) acc[r] += FEXP2(st[r]);
            }
        }
#pragma unroll
        for (int off = 1; off <= 16; off <<= 1)
#pragma unroll
            for (int r = 0; r < 16; ++r) acc[r] += __shfl_xor(acc[r], off, 64);
        if (l31 == 0) {
#pragma unroll
            for (int r = 0; r < 16; ++r) {
                int s_local = (r & 3) + 8 * (r >> 2) + 4 * hi;
                colLinv[(size_t)bh * TT + sbase + s_local] = 1.0f / acc[r];
            }
        }
    }
}

// ---------------------------------------------------------------------------
// Vt[bh][d][s] = VtRaw[bh][d][s] * colLinv[bh][s]; one block per (bh,d) row.
__global__ __launch_bounds__(256) void scale_vt(const unsigned short* __restrict__ VtRaw,
                                                const float* __restrict__ colLinv,
                                                unsigned short* __restrict__ Vt) {
    int bhd = blockIdx.x;            // bh*32 + d
    int bh = bhd >> 5;
    int s = threadIdx.x * 8;
    u16x8 v = *(const u16x8*)&VtRaw[(size_t)bhd * TT + s];
    const float4 i0 = *(const float4*)&colLinv[(size_t)bh * TT + s];
    const float4 i1 = *(const float4*)&colLinv[(size_t)bh * TT + s + 4];
    u16x8 o;
    o[0] = f2b(b2f(v[0]) * i0.x); o[1] = f2b(b2f(v[1]) * i0.y);
    o[2] = f2b(b2f(v[2]) * i0.z); o[3] = f2b(b2f(v[3]) * i0.w);
    o[4] = f2b(b2f(v[4]) * i1.x); o[5] = f2b(b2f(v[5]) * i1.y);
    o[6] = f2b(b2f(v[6]) * i1.z); o[7] = f2b(b2f(v[7]) * i1.w);
    *(u16x8*)&Vt[(size_t)bhd * TT + s] = o;
}

// ---------------------------------------------------------------------------
// Pass 2: O[t,:] = sum_{s<=t} exp2(q_t.k_s) * V'[s,:], xh = bf16(xn + O).
// Balanced: wave u handles t-tiles {u, 63-u} (65 chunks total per wave).
// Wave-private Pt (stride 36 ushorts: 72B rows -> <=2-way banks, 8B aligned),
// P read back as 2x b64. K/V prefetched one chunk ahead. No __syncthreads.
__global__ __launch_bounds__(256) void attn_out(const unsigned short* __restrict__ Qbf,
                                                const unsigned short* __restrict__ Kbf,
                                                const unsigned short* __restrict__ Vt,
                                                const float* __restrict__ xn,
                                                unsigned short* __restrict__ xh_bf) {
    __shared__ unsigned short Pt[128][36];
    int tid = threadIdx.x;
    int w = tid >> 6, lane = tid & 63, q = lane >> 4, col = lane & 15;
    int bh = blockIdx.y, b = bh >> 3, h = bh & 7;
    int u = blockIdx.x * 4 + w;               // 0..31
    int trow = w * 32;
    const unsigned short* Kb = Kbf + (size_t)bh * TT * 32;
    const unsigned short* Vb = Vt + (size_t)bh * 32 * TT;
    const f32x4 z = {};

#pragma unroll
    for (int phase = 0; phase < 2; ++phase) {
        int tt = phase ? (63 - u) : u;
        int tbase = tt * 32;
        const unsigned short* Qrow = Qbf + ((size_t)bh * TT + tbase) * 32;
        bf16x8 q0 = ld8(Qrow + (size_t)col * 32 + q * 8);          // t 0..15
        bf16x8 q1 = ld8(Qrow + (size_t)(16 + col) * 32 + q * 8);   // t 16..31
        f32x4 o00 = z, o01 = z, o10 = z, o11 = z;   // [tsub][dsub]

        bf16x8 ck0 = ld8(Kb + (size_t)col * 32 + q * 8);          // s 0..15
        bf16x8 ck1 = ld8(Kb + (size_t)(16 + col) * 32 + q * 8);   // s 16..31
        bf16x8 cv0 = ld8(Vb + (size_t)col * TT + q * 8);          // d 0..15
        bf16x8 cv1 = ld8(Vb + (size_t)(16 + col) * TT + q * 8);   // d 16..31

        for (int s0 = 0; s0 <= tbase; s0 += 32) {
            bool diag = (s0 == tbase);
            // S^T tiles: C-layout col=t_local, row=q*4+r=s_local
            f32x4 st00 = MFMA16(ck0, q0, z);
            f32x4 st01 = MFMA16(ck0, q1, z);
            f32x4 st11 = MFMA16(ck1, q1, z);
            f32x4 st10 = diag ? z : MFMA16(ck1, q0, z);
            // prefetch next chunk
            int sn = s0 + 32;
            if (sn <= tbase) {
                ck0 = ld8(Kb + (size_t)(sn + col) * 32 + q * 8);
                ck1 = ld8(Kb + (size_t)(sn + 16 + col) * 32 + q * 8);
            }
            uint2 w0, w1, w2, w3;
            if (diag) {   // mask s_g <= t_g
                float e0[4], e1[4], e3[4];
#pragma unroll
                for (int r = 0; r < 4; ++r) {
                    int sl = q * 4 + r;
                    e0[r] = (sl <= col) ? FEXP2(st00[r]) : 0.f;
                    e1[r] = FEXP2(st01[r]);              // s<16<=t: full
                    e3[r] = (sl <= col) ? FEXP2(st11[r]) : 0.f;
                }
                w0.x = pk_bf16(e0[0], e0[1]); w0.y = pk_bf16(e0[2], e0[3]);
                w1.x = pk_bf16(e1[0], e1[1]); w1.y = pk_bf16(e1[2], e1[3]);
                w2.x = 0u;                    w2.y = 0u;
                w3.x = pk_bf16(e3[0], e3[1]); w3.y = pk_bf16(e3[2], e3[3]);
            } else {
                w0.x = pk_bf16(FEXP2(st00[0]), FEXP2(st00[1]));
                w0.y = pk_bf16(FEXP2(st00[2]), FEXP2(st00[3]));
                w1.x = pk_bf16(FEXP2(st01[0]), FEXP2(st01[1]));
                w1.y = pk_bf16(FEXP2(st01[2]), FEXP2(st01[3]));
                w2.x = pk_bf16(FEXP2(st10[0]), FEXP2(st10[1]));
                w2.y = pk_bf16(FEXP2(st10[2]), FEXP2(st10[3]));
                w3.x = pk_bf16(FEXP2(st11[0]), FEXP2(st11[1]));
                w3.y = pk_bf16(FEXP2(st11[2]), FEXP2(st11[3]));
            }
            *(uint2*)&Pt[trow + col][q * 4]           = w0;
            *(uint2*)&Pt[trow + 16 + col][q * 4]      = w1;
            *(uint2*)&Pt[trow + col][16 + q * 4]      = w2;
            *(uint2*)&Pt[trow + 16 + col][16 + q * 4] = w3;
            // P A-frags: two 8B reads each (rows are 8B aligned at stride 36)
            union { uint2 u2[2]; bf16x8 v; } p0u, p1u;
            p0u.u2[0] = *(const uint2*)&Pt[trow + col][q * 8];
            p0u.u2[1] = *(const uint2*)&Pt[trow + col][q * 8 + 4];
            p1u.u2[0] = *(const uint2*)&Pt[trow + 16 + col][q * 8];
            p1u.u2[1] = *(const uint2*)&Pt[trow + 16 + col][q * 8 + 4];
            // PV
            o00 = MFMA16(p0u.v, cv0, o00);
            o01 = MFMA16(p0u.v, cv1, o01);
            o10 = MFMA16(p1u.v, cv0, o10);
            o11 = MFMA16(p1u.v, cv1, o11);
            if (sn <= tbase) {
                cv0 = ld8(Vb + (size_t)col * TT + sn + q * 8);
                cv1 = ld8(Vb + (size_t)(16 + col) * TT + sn + q * 8);
            }
        }

        // Epilogue: C-layout col=d_local, row=q*4+r=t_local; xh = xn + O
#pragma unroll
        for (int r = 0; r < 4; ++r) {
            int t0g = tbase + q * 4 + r;
            int t1g = tbase + 16 + q * 4 + r;
            size_t i00 = ((size_t)(b * TT) + t0g) * TE + h * 32 + col;
            size_t i10 = ((size_t)(b * TT) + t1g) * TE + h * 32 + col;
            xh_bf[i00]      = f2b(o00[r] + xn[i00]);
            xh_bf[i00 + 16] = f2b(o01[r] + xn[i00 + 16]);
            xh_bf[i10]      = f2b(o10[r] + xn[i10]);
            xh_bf[i10 + 16] = f2b(o11[r] + xn[i10 + 16]);
        }
    }
}

// ---------------------------------------------------------------------------
extern "C" void kernel_launch(void* const* d_in, const int* in_sizes, int n_in,
                              void* d_out, int out_size, void* d_ws, size_t ws_size,
                              hipStream_t stream) {
    (void)in_sizes; (void)n_in; (void)out_size; (void)ws_size;
    const float* x     = (const float*)d_in[0];
    const float* wq    = (const float*)d_in[1];
    const float* wk    = (const float*)d_in[2];
    const float* wv    = (const float*)d_in[3];
    const float* w_lin = (const float*)d_in[4];
    const float* b_lin = (const float*)d_in[5];
    const float* g1    = (const float*)d_in[6];
    const float* beta1 = (const float*)d_in[7];
    const float* g2    = (const float*)d_in[8];
    const float* beta2 = (const float*)d_in[9];
    const float* w_f1  = (const float*)d_in[10];
    const float* b_f1  = (const float*)d_in[11];
    const float* w_f2  = (const float*)d_in[12];
    const float* b_f2  = (const float*)d_in[13];
    float* out = (float*)d_out;

    char* ws = (char*)d_ws;
    unsigned short* Wqkv_t = (unsigned short*)(ws + 0);         //  384 KB
    unsigned short* Wlin_t = (unsigned short*)(ws + 393216);    //  128 KB
    unsigned short* Wf1_t  = (unsigned short*)(ws + 524288);    //  512 KB
    unsigned short* Wf2_t  = (unsigned short*)(ws + 1048576);   //  512 KB
    float*          xn     = (float*)(ws + 1572864);            //   16 MB  [xl aliases]
    unsigned short* xn_bf  = (unsigned short*)(ws + 18350080);  //    8 MB  [x2_bf aliases]
    unsigned short* Qbf    = (unsigned short*)(ws + 26738688);  //    8 MB ┐
    unsigned short* Kbf    = (unsigned short*)(ws + 35127296);  //    8 MB ├ h_bf aliases (32 MB)
    unsigned short* VtRaw  = (unsigned short*)(ws + 43515904);  //    8 MB │
    unsigned short* Vt     = (unsigned short*)(ws + 51904512);  //    8 MB ┘
    unsigned short* xh_bf  = (unsigned short*)(ws + 60293120);  //    8 MB
    float*          x2     = (float*)(ws + 68681728);           //   16 MB
    float*          colLinv= (float*)(ws + 85459072);           //  512 KB
    float*          xl     = xn;
    unsigned short* x2_bf  = xn_bf;
    unsigned short* h_bf   = Qbf;

    conv_w<<<3072, 256, 0, stream>>>(wq, wk, wv, w_lin, w_f1, w_f2,
                                     Wqkv_t, Wlin_t, Wf1_t, Wf2_t);
    ln_w<<<4096, 256, 0, stream>>>(x, g1, beta1, xn, xn_bf);
    gemm_qkv<<<dim3(6, 128), 256, 0, stream>>>(xn_bf, Wqkv_t, Qbf, Kbf, VtRaw);
    attn_cols<<<dim3(8, 64), 256, 0, stream>>>(Qbf, Kbf, colLinv);
    scale_vt<<<2048, 256, 0, stream>>>(VtRaw, colLinv, Vt);
    attn_out<<<dim3(8, 64), 256, 0, stream>>>(Qbf, Kbf, Vt, xn, xh_bf);
    gemm64<256><<<dim3(2, 128), 256, 0, stream>>>(xh_bf, Wlin_t, b_lin, nullptr,
                                                  xl, nullptr, 256, 0);
    ln_w<<<4096, 256, 0, stream>>>(xl, g2, beta2, x2, x2_bf);
    gemm64<256><<<dim3(8, 128), 256, 0, stream>>>(x2_bf, Wf1_t, b_f1, nullptr,
                                                  nullptr, h_bf, 1024, 1);
    gemm64<1024><<<dim3(2, 128), 256, 0, stream>>>(h_bf, Wf2_t, b_f2, x2,
                                                   out, nullptr, 256, 0);
}

// Round 7
// 343.606 us; speedup vs baseline: 1.3678x; 1.1129x over previous
//
#include <hip/hip_runtime.h>
#include <math.h>

// B=8, T=2048, E=256, H=8, D=32, F=1024
#define TT 2048
#define TE 256
// Q pre-scale: 256^-0.5 * log2(e)  (so softmax exp == exp2 of scores)
#define QSCALE (0.0625f * 1.44269504088896f)

typedef short  bf16x8 __attribute__((ext_vector_type(8)));
typedef float  f32x4  __attribute__((ext_vector_type(4)));
typedef float  f32x16 __attribute__((ext_vector_type(16)));
typedef unsigned short u16x4 __attribute__((ext_vector_type(4)));
typedef unsigned short u16x8 __attribute__((ext_vector_type(8)));

__device__ __forceinline__ unsigned short f2b(float f) {
    union { float f; unsigned int u; } v; v.f = f;
    unsigned int r = v.u + 0x7FFF + ((v.u >> 16) & 1);   // RNE
    return (unsigned short)(r >> 16);
}
__device__ __forceinline__ float b2f(unsigned short u) {
    union { unsigned int i; float f; } v; v.i = ((unsigned int)u) << 16;
    return v.f;
}
#if __has_builtin(__builtin_amdgcn_cvt_pk_bf16_f32)
__device__ __forceinline__ unsigned int pk_bf16(float a, float b) {
    typedef __bf16 bf2 __attribute__((ext_vector_type(2)));
    union { bf2 v; unsigned int u; } u;
    u.v = __builtin_amdgcn_cvt_pk_bf16_f32(a, b);
    return u.u;
}
#else
__device__ __forceinline__ unsigned int pk_bf16(float a, float b) {
    return (unsigned int)f2b(a) | ((unsigned int)f2b(b) << 16);
}
#endif
// Native exp2 (single v_exp_f32) — exp2f w/o fast-math is the slow OCML path.
#if __has_builtin(__builtin_amdgcn_exp2f)
#define FEXP2(x) __builtin_amdgcn_exp2f(x)
#else
#define FEXP2(x) __expf(0.69314718056f * (x))
#endif
__device__ __forceinline__ bf16x8 ld8(const unsigned short* p) {
    return *(const bf16x8*)p;
}
#define MFMA16(a, b, c) __builtin_amdgcn_mfma_f32_16x16x32_bf16((a), (b), (c), 0, 0, 0)
#define MFMA32(a, b, c) __builtin_amdgcn_mfma_f32_32x32x16_bf16((a), (b), (c), 0, 0, 0)

// ---------------------------------------------------------------------------
// Weight convert/transpose to bf16 [N][K] row-major
__global__ __launch_bounds__(256) void conv_w(const float* __restrict__ wq,
                                              const float* __restrict__ wk,
                                              const float* __restrict__ wv,
                                              const float* __restrict__ w_lin,
                                              const float* __restrict__ w_f1,
                                              const float* __restrict__ w_f2,
                                              unsigned short* __restrict__ Wqkv,
                                              unsigned short* __restrict__ Wlin,
                                              unsigned short* __restrict__ Wf1,
                                              unsigned short* __restrict__ Wf2) {
    int idx = blockIdx.x * 256 + threadIdx.x;
    if (idx < 196608) {                       // Wqkv_t [768][256]
        int n = idx >> 8, k = idx & 255;
        int which = n >> 8, h = (n >> 5) & 7, d = n & 31;
        const float* w = (which == 0) ? wq : (which == 1) ? wk : wv;
        Wqkv[idx] = f2b(w[(h * 256 + k) * 32 + d]);
    } else if (idx < 262144) {                // Wlin_t [256][256]
        int i = idx - 196608; int n = i >> 8, k = i & 255;
        Wlin[i] = f2b(w_lin[k * 256 + n]);
    } else if (idx < 524288) {                // Wf1_t [1024][256]
        int i = idx - 262144; int n = i >> 8, k = i & 255;
        Wf1[i] = f2b(w_f1[k * 1024 + n]);
    } else {                                  // Wf2_t [256][1024]
        int i = idx - 524288; int n = i >> 10, k = i & 1023;
        Wf2[i] = f2b(w_f2[k * 256 + n]);
    }
}

// ---------------------------------------------------------------------------
// LayerNorm, wave-per-row (E=256 = 64 lanes x float4), shuffle reduce, no LDS
__global__ __launch_bounds__(256) void ln_w(const float* __restrict__ X,
                                            const float* __restrict__ g,
                                            const float* __restrict__ bta,
                                            float* __restrict__ Y,
                                            unsigned short* __restrict__ Yb) {
    int row = blockIdx.x * 4 + (threadIdx.x >> 6);
    int lane = threadIdx.x & 63;
    const float4 v = *(const float4*)&X[(size_t)row * TE + lane * 4];
    float s = v.x + v.y + v.z + v.w;
    float s2 = v.x * v.x + v.y * v.y + v.z * v.z + v.w * v.w;
#pragma unroll
    for (int off = 1; off <= 32; off <<= 1) {
        s  += __shfl_xor(s,  off, 64);
        s2 += __shfl_xor(s2, off, 64);
    }
    float mean = s * (1.0f / TE);
    float var = s2 * (1.0f / TE) - mean * mean;
    float rstd = rsqrtf(var + 1e-5f);
    const float4 gg = *(const float4*)&g[lane * 4];
    const float4 bb = *(const float4*)&bta[lane * 4];
    float4 o;
    o.x = (v.x - mean) * rstd * gg.x + bb.x;
    o.y = (v.y - mean) * rstd * gg.y + bb.y;
    o.z = (v.z - mean) * rstd * gg.z + bb.z;
    o.w = (v.w - mean) * rstd * gg.w + bb.w;
    if (Y) *(float4*)&Y[(size_t)row * TE + lane * 4] = o;
    if (Yb) {
        u16x4 ob = { f2b(o.x), f2b(o.y), f2b(o.z), f2b(o.w) };
        *(u16x4*)&Yb[(size_t)row * TE + lane * 4] = ob;
    }
}

// ---------------------------------------------------------------------------
// bf16 MFMA GEMM: C[M,N] = A[M,K] @ Wt[N,K]^T.
// Wave tile 64m x 64n (16 MFMA per 8 loads); block = 2x2 waves = 128x128.
template<int K>
__global__ __launch_bounds__(256, 2) void gemm64(const unsigned short* __restrict__ A,
                                                 const unsigned short* __restrict__ Bt,
                                                 const float* __restrict__ bias,
                                                 const float* __restrict__ resid,
                                                 float* __restrict__ outF,
                                                 unsigned short* __restrict__ outB,
                                                 int N, int relu) {
    int tid = threadIdx.x;
    int w = tid >> 6, lane = tid & 63, q = lane >> 4, col = lane & 15;
    int wm = w & 1, wn = w >> 1;
    int m0 = blockIdx.y * 128 + wm * 64;
    int n0 = blockIdx.x * 128 + wn * 64;
    f32x4 acc[4][4] = {};
    const unsigned short* ar = A + (size_t)(m0 + col) * K + q * 8;
    const unsigned short* bp = Bt + (size_t)(n0 + col) * K + q * 8;
#pragma unroll 2
    for (int k0 = 0; k0 < K; k0 += 32) {
        bf16x8 a[4], b[4];
#pragma unroll
        for (int i = 0; i < 4; ++i) a[i] = ld8(ar + (size_t)(i * 16) * K + k0);
#pragma unroll
        for (int j = 0; j < 4; ++j) b[j] = ld8(bp + (size_t)(j * 16) * K + k0);
#pragma unroll
        for (int i = 0; i < 4; ++i)
#pragma unroll
            for (int j = 0; j < 4; ++j)
                acc[i][j] = MFMA16(a[i], b[j], acc[i][j]);
    }
#pragma unroll
    for (int i = 0; i < 4; ++i)
#pragma unroll
    for (int j = 0; j < 4; ++j) {
        int n = n0 + j * 16 + col;
#pragma unroll
        for (int r = 0; r < 4; ++r) {
            int m = m0 + i * 16 + q * 4 + r;
            float v = acc[i][j][r];
            if (bias) v += bias[n];
            if (relu) v = fmaxf(v, 0.f);
            if (resid) v += resid[(size_t)m * N + n];
            if (outF) outF[(size_t)m * N + n] = v;
            if (outB) outB[(size_t)m * N + n] = f2b(v);
        }
    }
}

// ---------------------------------------------------------------------------
// QKV GEMM (K=256), wave tile 64x64. Epilogue scatter: Qbf (x QSCALE), Kbf in
// [bh][t][32]; V^T (unscaled bf16) in [bh][d][TT] with packed uint2 stores.
__global__ __launch_bounds__(256, 2) void gemm_qkv(const unsigned short* __restrict__ A,
                                                   const unsigned short* __restrict__ Bt,
                                                   unsigned short* __restrict__ Qbf,
                                                   unsigned short* __restrict__ Kbf,
                                                   unsigned short* __restrict__ VtRaw) {
    const int K = 256;
    int tid = threadIdx.x;
    int w = tid >> 6, lane = tid & 63, q = lane >> 4, col = lane & 15;
    int wm = w & 1, wn = w >> 1;
    int m0 = blockIdx.y * 128 + wm * 64;
    int n0 = blockIdx.x * 128 + wn * 64;
    f32x4 acc[4][4] = {};
    const unsigned short* ar = A + (size_t)(m0 + col) * K + q * 8;
    const unsigned short* bp = Bt + (size_t)(n0 + col) * K + q * 8;
#pragma unroll 2
    for (int k0 = 0; k0 < K; k0 += 32) {
        bf16x8 a[4], b[4];
#pragma unroll
        for (int i = 0; i < 4; ++i) a[i] = ld8(ar + (size_t)(i * 16) * K + k0);
#pragma unroll
        for (int j = 0; j < 4; ++j) b[j] = ld8(bp + (size_t)(j * 16) * K + k0);
#pragma unroll
        for (int i = 0; i < 4; ++i)
#pragma unroll
            for (int j = 0; j < 4; ++j)
                acc[i][j] = MFMA16(a[i], b[j], acc[i][j]);
    }
#pragma unroll
    for (int i = 0; i < 4; ++i)
#pragma unroll
    for (int j = 0; j < 4; ++j) {
        int n = n0 + j * 16 + col;
        int which = n >> 8, h = (n >> 5) & 7, d = n & 31;
        int m = m0 + i * 16 + q * 4;
        int b = m >> 11, t = m & 2047;
        int bh = b * 8 + h;
        if (which == 0) {
#pragma unroll
            for (int r = 0; r < 4; ++r)
                Qbf[((size_t)bh * TT + t + r) * 32 + d] = f2b(acc[i][j][r] * QSCALE);
        } else if (which == 1) {
#pragma unroll
            for (int r = 0; r < 4; ++r)
                Kbf[((size_t)bh * TT + t + r) * 32 + d] = f2b(acc[i][j][r]);
        } else {
            uint2 pv;
            pv.x = pk_bf16(acc[i][j][0], acc[i][j][1]);
            pv.y = pk_bf16(acc[i][j][2], acc[i][j][3]);
            *(uint2*)&VtRaw[((size_t)bh * 32 + d) * TT + t] = pv;
        }
    }
}

// ---------------------------------------------------------------------------
// Pass 1: colLinv[s] = 1 / sum_{t>=s} exp2(q_t . k_s).
// Block = 4 waves co-owning s-tile pair {u, 63-u}: wave w takes t-chunks
// ct = stile+w, +4, ... ; partial sums combined in LDS. Balanced + 4x waves.
__global__ __launch_bounds__(256, 4) void attn_cols(const unsigned short* __restrict__ Qbf,
                                                    const unsigned short* __restrict__ Kbf,
                                                    float* __restrict__ colLinv) {
    __shared__ float Lb[4][32];
    int tid = threadIdx.x;
    int w = tid >> 6, lane = tid & 63, hi = lane >> 5, l31 = lane & 31;
    int bh = blockIdx.y;
    int u = blockIdx.x;                       // 0..31
    const unsigned short* Qb = Qbf + (size_t)bh * TT * 32;
    const unsigned short* Kb = Kbf + (size_t)bh * TT * 32;
    const f32x16 z16 = {};
#pragma unroll
    for (int phase = 0; phase < 2; ++phase) {
        int stile = phase ? (63 - u) : u;
        int sbase = stile * 32;
        bf16x8 a0 = ld8(Kb + (size_t)(sbase + l31) * 32 + hi * 8);        // d 0..15
        bf16x8 a1 = ld8(Kb + (size_t)(sbase + l31) * 32 + 16 + hi * 8);   // d 16..31
        float acc[16] = {};
        for (int ct = stile + w; ct < 64; ct += 4) {
            int t0 = ct * 32;
            bf16x8 q0 = ld8(Qb + (size_t)(t0 + l31) * 32 + hi * 8);
            bf16x8 q1 = ld8(Qb + (size_t)(t0 + l31) * 32 + 16 + hi * 8);
            f32x16 st = MFMA32(a0, q0, z16);
            st = MFMA32(a1, q1, st);
            if (ct == stile) {
#pragma unroll
                for (int r = 0; r < 16; ++r) {
                    int s_local = (r & 3) + 8 * (r >> 2) + 4 * hi;
                    acc[r] += (l31 >= s_local) ? FEXP2(st[r]) : 0.f;
                }
            } else {
#pragma unroll
                for (int r = 0; r < 16; ++r) acc[r] += FEXP2(st[r]);
            }
        }
#pragma unroll
        for (int off = 1; off <= 16; off <<= 1)
#pragma unroll
            for (int r = 0; r < 16; ++r) acc[r] += __shfl_xor(acc[r], off, 64);
        if (l31 == 0) {
#pragma unroll
            for (int r = 0; r < 16; ++r) {
                int s_local = (r & 3) + 8 * (r >> 2) + 4 * hi;
                Lb[w][s_local] = acc[r];
            }
        }
        __syncthreads();
        if (tid < 32) {
            float s = Lb[0][tid] + Lb[1][tid] + Lb[2][tid] + Lb[3][tid];
            colLinv[(size_t)bh * TT + sbase + tid] = 1.0f / s;
        }
        __syncthreads();
    }
}

// ---------------------------------------------------------------------------
// Vt[bh][d][s] = VtRaw[bh][d][s] * colLinv[bh][s]; one block per (bh,d) row.
__global__ __launch_bounds__(256) void scale_vt(const unsigned short* __restrict__ VtRaw,
                                                const float* __restrict__ colLinv,
                                                unsigned short* __restrict__ Vt) {
    int bhd = blockIdx.x;            // bh*32 + d
    int bh = bhd >> 5;
    int s = threadIdx.x * 8;
    u16x8 v = *(const u16x8*)&VtRaw[(size_t)bhd * TT + s];
    const float4 i0 = *(const float4*)&colLinv[(size_t)bh * TT + s];
    const float4 i1 = *(const float4*)&colLinv[(size_t)bh * TT + s + 4];
    u16x8 o;
    o[0] = f2b(b2f(v[0]) * i0.x); o[1] = f2b(b2f(v[1]) * i0.y);
    o[2] = f2b(b2f(v[2]) * i0.z); o[3] = f2b(b2f(v[3]) * i0.w);
    o[4] = f2b(b2f(v[4]) * i1.x); o[5] = f2b(b2f(v[5]) * i1.y);
    o[6] = f2b(b2f(v[6]) * i1.z); o[7] = f2b(b2f(v[7]) * i1.w);
    *(u16x8*)&Vt[(size_t)bhd * TT + s] = o;
}

// ---------------------------------------------------------------------------
// Pass 2: O[t,:] = sum_{s<=t} exp2(q_t.k_s) * V'[s,:], xh = bf16(xn + O).
// Block = 4 waves co-owning t-tile pair {u, 63-u} (2 phases). Wave w takes
// s-chunks c = w, w+4, ...; partial O combined in LDS (1 barrier/phase).
// Wave-private Pt; S^T=K.Q^T trick (packed b64 LDS writes/reads).
__global__ __launch_bounds__(256, 4) void attn_out(const unsigned short* __restrict__ Qbf,
                                                   const unsigned short* __restrict__ Kbf,
                                                   const unsigned short* __restrict__ Vt,
                                                   const float* __restrict__ xn,
                                                   unsigned short* __restrict__ xh_bf) {
    __shared__ unsigned short Pt[4][32][36];   // 9216 B, wave-private P tiles
    __shared__ float Ob[4][32][36];            // 18432 B, partial-O combine
    int tid = threadIdx.x;
    int w = tid >> 6, lane = tid & 63, q = lane >> 4, col = lane & 15;
    int bh = blockIdx.y, b = bh >> 3, h = bh & 7;
    int u = blockIdx.x;                        // 0..31
    const unsigned short* Kb = Kbf + (size_t)bh * TT * 32;
    const unsigned short* Vb = Vt + (size_t)bh * 32 * TT;
    const f32x4 z = {};

#pragma unroll
    for (int phase = 0; phase < 2; ++phase) {
        int tt = phase ? (63 - u) : u;
        int tbase = tt * 32;
        const unsigned short* Qrow = Qbf + ((size_t)bh * TT + tbase) * 32;
        bf16x8 q0 = ld8(Qrow + (size_t)col * 32 + q * 8);          // t 0..15
        bf16x8 q1 = ld8(Qrow + (size_t)(16 + col) * 32 + q * 8);   // t 16..31
        f32x4 o00 = z, o01 = z, o10 = z, o11 = z;   // [tsub][dsub]

        int c = w;
        bf16x8 ck0 = ld8(Kb + (size_t)(c * 32 + col) * 32 + q * 8);
        bf16x8 ck1 = ld8(Kb + (size_t)(c * 32 + 16 + col) * 32 + q * 8);
        bf16x8 cv0 = ld8(Vb + (size_t)col * TT + c * 32 + q * 8);
        bf16x8 cv1 = ld8(Vb + (size_t)(16 + col) * TT + c * 32 + q * 8);

        for (; c <= tt; c += 4) {
            bool diag = (c == tt);
            // S^T tiles: C-layout col=t_local, row=q*4+r=s_local
            f32x4 st00 = MFMA16(ck0, q0, z);
            f32x4 st01 = MFMA16(ck0, q1, z);
            f32x4 st11 = MFMA16(ck1, q1, z);
            f32x4 st10 = diag ? z : MFMA16(ck1, q0, z);
            // prefetch next chunk (c+4)
            int cn = c + 4;
            if (cn <= tt) {
                ck0 = ld8(Kb + (size_t)(cn * 32 + col) * 32 + q * 8);
                ck1 = ld8(Kb + (size_t)(cn * 32 + 16 + col) * 32 + q * 8);
            }
            uint2 w0, w1, w2, w3;
            if (diag) {   // mask s_g <= t_g
                float e0[4], e1[4], e3[4];
#pragma unroll
                for (int r = 0; r < 4; ++r) {
                    int sl = q * 4 + r;
                    e0[r] = (sl <= col) ? FEXP2(st00[r]) : 0.f;
                    e1[r] = FEXP2(st01[r]);              // s<16<=t: full
                    e3[r] = (sl <= col) ? FEXP2(st11[r]) : 0.f;
                }
                w0.x = pk_bf16(e0[0], e0[1]); w0.y = pk_bf16(e0[2], e0[3]);
                w1.x = pk_bf16(e1[0], e1[1]); w1.y = pk_bf16(e1[2], e1[3]);
                w2.x = 0u;                    w2.y = 0u;
                w3.x = pk_bf16(e3[0], e3[1]); w3.y = pk_bf16(e3[2], e3[3]);
            } else {
                w0.x = pk_bf16(FEXP2(st00[0]), FEXP2(st00[1]));
                w0.y = pk_bf16(FEXP2(st00[2]), FEXP2(st00[3]));
                w1.x = pk_bf16(FEXP2(st01[0]), FEXP2(st01[1]));
                w1.y = pk_bf16(FEXP2(st01[2]), FEXP2(st01[3]));
                w2.x = pk_bf16(FEXP2(st10[0]), FEXP2(st10[1]));
                w2.y = pk_bf16(FEXP2(st10[2]), FEXP2(st10[3]));
                w3.x = pk_bf16(FEXP2(st11[0]), FEXP2(st11[1]));
                w3.y = pk_bf16(FEXP2(st11[2]), FEXP2(st11[3]));
            }
            *(uint2*)&Pt[w][col][q * 4]           = w0;
            *(uint2*)&Pt[w][16 + col][q * 4]      = w1;
            *(uint2*)&Pt[w][col][16 + q * 4]      = w2;
            *(uint2*)&Pt[w][16 + col][16 + q * 4] = w3;
            // P A-frags: two 8B reads each (rows 8B aligned at stride 36)
            union { uint2 u2[2]; bf16x8 v; } p0u, p1u;
            p0u.u2[0] = *(const uint2*)&Pt[w][col][q * 8];
            p0u.u2[1] = *(const uint2*)&Pt[w][col][q * 8 + 4];
            p1u.u2[0] = *(const uint2*)&Pt[w][16 + col][q * 8];
            p1u.u2[1] = *(const uint2*)&Pt[w][16 + col][q * 8 + 4];
            // PV
            o00 = MFMA16(p0u.v, cv0, o00);
            o01 = MFMA16(p0u.v, cv1, o01);
            o10 = MFMA16(p1u.v, cv0, o10);
            o11 = MFMA16(p1u.v, cv1, o11);
            if (cn <= tt) {
                cv0 = ld8(Vb + (size_t)col * TT + cn * 32 + q * 8);
                cv1 = ld8(Vb + (size_t)(16 + col) * TT + cn * 32 + q * 8);
            }
        }

        // Partial-O to LDS (C-layout: row=q*4+r=t_local, col=d_local)
#pragma unroll
        for (int r = 0; r < 4; ++r) {
            Ob[w][q * 4 + r][col]           = o00[r];
            Ob[w][q * 4 + r][16 + col]      = o01[r];
            Ob[w][16 + q * 4 + r][col]      = o10[r];
            Ob[w][16 + q * 4 + r][16 + col] = o11[r];
        }
        __syncthreads();
        // Combine 4 partials + epilogue: 256 thr = 32 rows x 8 col-quads
        {
            int row = tid >> 3;
            int c4 = (tid & 7) * 4;
            float4 s0 = *(const float4*)&Ob[0][row][c4];
            float4 s1 = *(const float4*)&Ob[1][row][c4];
            float4 s2 = *(const float4*)&Ob[2][row][c4];
            float4 s3 = *(const float4*)&Ob[3][row][c4];
            size_t base = ((size_t)(b * TT) + tbase + row) * TE + h * 32 + c4;
            const float4 xv = *(const float4*)&xn[base];
            u16x4 ob = { f2b(s0.x + s1.x + s2.x + s3.x + xv.x),
                         f2b(s0.y + s1.y + s2.y + s3.y + xv.y),
                         f2b(s0.z + s1.z + s2.z + s3.z + xv.z),
                         f2b(s0.w + s1.w + s2.w + s3.w + xv.w) };
            *(u16x4*)&xh_bf[base] = ob;
        }
        __syncthreads();   // Ob reused next phase
    }
}

// ---------------------------------------------------------------------------
extern "C" void kernel_launch(void* const* d_in, const int* in_sizes, int n_in,
                              void* d_out, int out_size, void* d_ws, size_t ws_size,
                              hipStream_t stream) {
    (void)in_sizes; (void)n_in; (void)out_size; (void)ws_size;
    const float* x     = (const float*)d_in[0];
    const float* wq    = (const float*)d_in[1];
    const float* wk    = (const float*)d_in[2];
    const float* wv    = (const float*)d_in[3];
    const float* w_lin = (const float*)d_in[4];
    const float* b_lin = (const float*)d_in[5];
    const float* g1    = (const float*)d_in[6];
    const float* beta1 = (const float*)d_in[7];
    const float* g2    = (const float*)d_in[8];
    const float* beta2 = (const float*)d_in[9];
    const float* w_f1  = (const float*)d_in[10];
    const float* b_f1  = (const float*)d_in[11];
    const float* w_f2  = (const float*)d_in[12];
    const float* b_f2  = (const float*)d_in[13];
    float* out = (float*)d_out;

    char* ws = (char*)d_ws;
    unsigned short* Wqkv_t = (unsigned short*)(ws + 0);         //  384 KB
    unsigned short* Wlin_t = (unsigned short*)(ws + 393216);    //  128 KB
    unsigned short* Wf1_t  = (unsigned short*)(ws + 524288);    //  512 KB
    unsigned short* Wf2_t  = (unsigned short*)(ws + 1048576);   //  512 KB
    float*          xn     = (float*)(ws + 1572864);            //   16 MB  [xl aliases]
    unsigned short* xn_bf  = (unsigned short*)(ws + 18350080);  //    8 MB  [x2_bf aliases]
    unsigned short* Qbf    = (unsigned short*)(ws + 26738688);  //    8 MB ┐
    unsigned short* Kbf    = (unsigned short*)(ws + 35127296);  //    8 MB ├ h_bf aliases (32 MB)
    unsigned short* VtRaw  = (unsigned short*)(ws + 43515904);  //    8 MB │
    unsigned short* Vt     = (unsigned short*)(ws + 51904512);  //    8 MB ┘
    unsigned short* xh_bf  = (unsigned short*)(ws + 60293120);  //    8 MB
    float*          x2     = (float*)(ws + 68681728);           //   16 MB
    float*          colLinv= (float*)(ws + 85459072);           //  512 KB
    float*          xl     = xn;
    unsigned short* x2_bf  = xn_bf;
    unsigned short* h_bf   = Qbf;

    conv_w<<<3072, 256, 0, stream>>>(wq, wk, wv, w_lin, w_f1, w_f2,
                                     Wqkv_t, Wlin_t, Wf1_t, Wf2_t);
    ln_w<<<4096, 256, 0, stream>>>(x, g1, beta1, xn, xn_bf);
    gemm_qkv<<<dim3(6, 128), 256, 0, stream>>>(xn_bf, Wqkv_t, Qbf, Kbf, VtRaw);
    attn_cols<<<dim3(32, 64), 256, 0, stream>>>(Qbf, Kbf, colLinv);
    scale_vt<<<2048, 256, 0, stream>>>(VtRaw, colLinv, Vt);
    attn_out<<<dim3(32, 64), 256, 0, stream>>>(Qbf, Kbf, Vt, xn, xh_bf);
    gemm64<256><<<dim3(2, 128), 256, 0, stream>>>(xh_bf, Wlin_t, b_lin, nullptr,
                                                  xl, nullptr, 256, 0);
    ln_w<<<4096, 256, 0, stream>>>(xl, g2, beta2, x2, x2_bf);
    gemm64<256><<<dim3(8, 128), 256, 0, stream>>>(x2_bf, Wf1_t, b_f1, nullptr,
                                                  nullptr, h_bf, 1024, 1);
    gemm64<1024><<<dim3(2, 128), 256, 0, stream>>>(h_bf, Wf2_t, b_f2, x2,
                                                   out, nullptr, 256, 0);
}

// Round 8
// 310.424 us; speedup vs baseline: 1.5140x; 1.1069x over previous
//
#include <hip/hip_runtime.h>
#include <math.h>

// B=8, T=2048, E=256, H=8, D=32, F=1024
#define TT 2048
#define TE 256
// Q pre-scale: 256^-0.5 * log2(e)  (so softmax exp == exp2 of scores)
#define QSCALE (0.0625f * 1.44269504088896f)

typedef short  bf16x8 __attribute__((ext_vector_type(8)));
typedef float  f32x4  __attribute__((ext_vector_type(4)));
typedef float  f32x16 __attribute__((ext_vector_type(16)));
typedef unsigned short u16x4 __attribute__((ext_vector_type(4)));
typedef unsigned short u16x8 __attribute__((ext_vector_type(8)));

__device__ __forceinline__ unsigned short f2b(float f) {
    union { float f; unsigned int u; } v; v.f = f;
    unsigned int r = v.u + 0x7FFF + ((v.u >> 16) & 1);   // RNE
    return (unsigned short)(r >> 16);
}
__device__ __forceinline__ float b2f(unsigned short u) {
    union { unsigned int i; float f; } v; v.i = ((unsigned int)u) << 16;
    return v.f;
}
#if __has_builtin(__builtin_amdgcn_cvt_pk_bf16_f32)
__device__ __forceinline__ unsigned int pk_bf16(float a, float b) {
    typedef __bf16 bf2 __attribute__((ext_vector_type(2)));
    union { bf2 v; unsigned int u; } u;
    u.v = __builtin_amdgcn_cvt_pk_bf16_f32(a, b);
    return u.u;
}
#else
__device__ __forceinline__ unsigned int pk_bf16(float a, float b) {
    return (unsigned int)f2b(a) | ((unsigned int)f2b(b) << 16);
}
#endif
// Native exp2 (single v_exp_f32) — exp2f w/o fast-math is the slow OCML path.
#if __has_builtin(__builtin_amdgcn_exp2f)
#define FEXP2(x) __builtin_amdgcn_exp2f(x)
#else
#define FEXP2(x) __expf(0.69314718056f * (x))
#endif
__device__ __forceinline__ bf16x8 ld8(const unsigned short* p) {
    return *(const bf16x8*)p;
}
// Async global->LDS, 16B/lane. LDS dest = wave-uniform base + lane*16.
__device__ __forceinline__ void gl_lds16(const unsigned short* g, unsigned short* l) {
    __builtin_amdgcn_global_load_lds(
        (const __attribute__((address_space(1))) unsigned int*)(uintptr_t)g,
        (__attribute__((address_space(3))) unsigned int*)(uintptr_t)l,
        16, 0, 0);
}
#define MFMA16(a, b, c) __builtin_amdgcn_mfma_f32_16x16x32_bf16((a), (b), (c), 0, 0, 0)
#define MFMA32(a, b, c) __builtin_amdgcn_mfma_f32_32x32x16_bf16((a), (b), (c), 0, 0, 0)

// ---------------------------------------------------------------------------
// Weight convert/transpose to bf16 [N][K] row-major
__global__ __launch_bounds__(256) void conv_w(const float* __restrict__ wq,
                                              const float* __restrict__ wk,
                                              const float* __restrict__ wv,
                                              const float* __restrict__ w_lin,
                                              const float* __restrict__ w_f1,
                                              const float* __restrict__ w_f2,
                                              unsigned short* __restrict__ Wqkv,
                                              unsigned short* __restrict__ Wlin,
                                              unsigned short* __restrict__ Wf1,
                                              unsigned short* __restrict__ Wf2) {
    int idx = blockIdx.x * 256 + threadIdx.x;
    if (idx < 196608) {                       // Wqkv_t [768][256]
        int n = idx >> 8, k = idx & 255;
        int which = n >> 8, h = (n >> 5) & 7, d = n & 31;
        const float* w = (which == 0) ? wq : (which == 1) ? wk : wv;
        Wqkv[idx] = f2b(w[(h * 256 + k) * 32 + d]);
    } else if (idx < 262144) {                // Wlin_t [256][256]
        int i = idx - 196608; int n = i >> 8, k = i & 255;
        Wlin[i] = f2b(w_lin[k * 256 + n]);
    } else if (idx < 524288) {                // Wf1_t [1024][256]
        int i = idx - 262144; int n = i >> 8, k = i & 255;
        Wf1[i] = f2b(w_f1[k * 1024 + n]);
    } else {                                  // Wf2_t [256][1024]
        int i = idx - 524288; int n = i >> 10, k = i & 1023;
        Wf2[i] = f2b(w_f2[k * 256 + n]);
    }
}

// ---------------------------------------------------------------------------
// LayerNorm, wave-per-row (E=256 = 64 lanes x float4), shuffle reduce, no LDS
__global__ __launch_bounds__(256) void ln_w(const float* __restrict__ X,
                                            const float* __restrict__ g,
                                            const float* __restrict__ bta,
                                            float* __restrict__ Y,
                                            unsigned short* __restrict__ Yb) {
    int row = blockIdx.x * 4 + (threadIdx.x >> 6);
    int lane = threadIdx.x & 63;
    const float4 v = *(const float4*)&X[(size_t)row * TE + lane * 4];
    float s = v.x + v.y + v.z + v.w;
    float s2 = v.x * v.x + v.y * v.y + v.z * v.z + v.w * v.w;
#pragma unroll
    for (int off = 1; off <= 32; off <<= 1) {
        s  += __shfl_xor(s,  off, 64);
        s2 += __shfl_xor(s2, off, 64);
    }
    float mean = s * (1.0f / TE);
    float var = s2 * (1.0f / TE) - mean * mean;
    float rstd = rsqrtf(var + 1e-5f);
    const float4 gg = *(const float4*)&g[lane * 4];
    const float4 bb = *(const float4*)&bta[lane * 4];
    float4 o;
    o.x = (v.x - mean) * rstd * gg.x + bb.x;
    o.y = (v.y - mean) * rstd * gg.y + bb.y;
    o.z = (v.z - mean) * rstd * gg.z + bb.z;
    o.w = (v.w - mean) * rstd * gg.w + bb.w;
    if (Y) *(float4*)&Y[(size_t)row * TE + lane * 4] = o;
    if (Yb) {
        u16x4 ob = { f2b(o.x), f2b(o.y), f2b(o.z), f2b(o.w) };
        *(u16x4*)&Yb[(size_t)row * TE + lane * 4] = ob;
    }
}

// ---------------------------------------------------------------------------
// LDS-staged bf16 MFMA GEMM (m97 structure): C[M,N] = A[M,K] @ Wt[N,K]^T.
// Block 128x128 (2x2 waves, 64x64 wave tile), BK=32, global_load_lds width 16.
// Grid: (m-tiles = x, n-tiles = y) so same-A blocks are 128 apart -> same XCD.
template<int K>
__global__ __launch_bounds__(256) void gemm_lds(const unsigned short* __restrict__ A,
                                                const unsigned short* __restrict__ Bt,
                                                const float* __restrict__ bias,
                                                const float* __restrict__ resid,
                                                float* __restrict__ outF,
                                                unsigned short* __restrict__ outB,
                                                int N, int relu) {
    __shared__ unsigned short Al[128 * 32];
    __shared__ unsigned short Bl[128 * 32];
    int tid = threadIdx.x;
    int w = tid >> 6, lane = tid & 63, q = lane >> 4, col = lane & 15;
    int wm = w & 1, wn = w >> 1;
    int m0 = blockIdx.x * 128;
    int n0 = blockIdx.y * 128;
    f32x4 acc[4][4] = {};
    // Staging: wave w owns rows [32w, 32w+32) of both tiles, 2 instrs each.
    int srow = lane >> 2;            // 0..15
    int skq  = (lane & 3) * 8;       // k elem offset {0,8,16,24} (16B)
    const unsigned short* Ag0 = A  + (size_t)(m0 + w * 32 + srow) * K + skq;
    const unsigned short* Ag1 = Ag0 + (size_t)16 * K;
    const unsigned short* Bg0 = Bt + (size_t)(n0 + w * 32 + srow) * K + skq;
    const unsigned short* Bg1 = Bg0 + (size_t)16 * K;
    unsigned short* Asl0 = &Al[(w * 32) * 32];
    unsigned short* Asl1 = Asl0 + 16 * 32;
    unsigned short* Bsl0 = &Bl[(w * 32) * 32];
    unsigned short* Bsl1 = Bsl0 + 16 * 32;
    for (int k0 = 0; k0 < K; k0 += 32) {
        gl_lds16(Ag0 + k0, Asl0);
        gl_lds16(Ag1 + k0, Asl1);
        gl_lds16(Bg0 + k0, Bsl0);
        gl_lds16(Bg1 + k0, Bsl1);
        __syncthreads();             // drains vmcnt (compiler-inserted)
        bf16x8 a[4], b[4];
#pragma unroll
        for (int i = 0; i < 4; ++i)
            a[i] = ld8(&Al[(wm * 64 + i * 16 + col) * 32 + q * 8]);
#pragma unroll
        for (int j = 0; j < 4; ++j)
            b[j] = ld8(&Bl[(wn * 64 + j * 16 + col) * 32 + q * 8]);
#pragma unroll
        for (int i = 0; i < 4; ++i)
#pragma unroll
            for (int j = 0; j < 4; ++j)
                acc[i][j] = MFMA16(a[i], b[j], acc[i][j]);
        __syncthreads();             // protect LDS before next stage
    }
#pragma unroll
    for (int i = 0; i < 4; ++i)
#pragma unroll
    for (int j = 0; j < 4; ++j) {
        int n = n0 + wn * 64 + j * 16 + col;
#pragma unroll
        for (int r = 0; r < 4; ++r) {
            int m = m0 + wm * 64 + i * 16 + q * 4 + r;
            float v = acc[i][j][r];
            if (bias) v += bias[n];
            if (relu) v = fmaxf(v, 0.f);
            if (resid) v += resid[(size_t)m * N + n];
            if (outF) outF[(size_t)m * N + n] = v;
            if (outB) outB[(size_t)m * N + n] = f2b(v);
        }
    }
}

// ---------------------------------------------------------------------------
// QKV GEMM, same staged core (K=256). Epilogue scatter: Qbf (x QSCALE), Kbf
// in [bh][t][32]; V^T (unscaled bf16) in [bh][d][TT], packed uint2 stores.
__global__ __launch_bounds__(256) void gemm_qkv(const unsigned short* __restrict__ A,
                                                const unsigned short* __restrict__ Bt,
                                                unsigned short* __restrict__ Qbf,
                                                unsigned short* __restrict__ Kbf,
                                                unsigned short* __restrict__ VtRaw) {
    const int K = 256;
    __shared__ unsigned short Al[128 * 32];
    __shared__ unsigned short Bl[128 * 32];
    int tid = threadIdx.x;
    int w = tid >> 6, lane = tid & 63, q = lane >> 4, col = lane & 15;
    int wm = w & 1, wn = w >> 1;
    int m0 = blockIdx.x * 128;
    int n0 = blockIdx.y * 128;
    f32x4 acc[4][4] = {};
    int srow = lane >> 2;
    int skq  = (lane & 3) * 8;
    const unsigned short* Ag0 = A  + (size_t)(m0 + w * 32 + srow) * K + skq;
    const unsigned short* Ag1 = Ag0 + (size_t)16 * K;
    const unsigned short* Bg0 = Bt + (size_t)(n0 + w * 32 + srow) * K + skq;
    const unsigned short* Bg1 = Bg0 + (size_t)16 * K;
    unsigned short* Asl0 = &Al[(w * 32) * 32];
    unsigned short* Asl1 = Asl0 + 16 * 32;
    unsigned short* Bsl0 = &Bl[(w * 32) * 32];
    unsigned short* Bsl1 = Bsl0 + 16 * 32;
    for (int k0 = 0; k0 < K; k0 += 32) {
        gl_lds16(Ag0 + k0, Asl0);
        gl_lds16(Ag1 + k0, Asl1);
        gl_lds16(Bg0 + k0, Bsl0);
        gl_lds16(Bg1 + k0, Bsl1);
        __syncthreads();
        bf16x8 a[4], b[4];
#pragma unroll
        for (int i = 0; i < 4; ++i)
            a[i] = ld8(&Al[(wm * 64 + i * 16 + col) * 32 + q * 8]);
#pragma unroll
        for (int j = 0; j < 4; ++j)
            b[j] = ld8(&Bl[(wn * 64 + j * 16 + col) * 32 + q * 8]);
#pragma unroll
        for (int i = 0; i < 4; ++i)
#pragma unroll
            for (int j = 0; j < 4; ++j)
                acc[i][j] = MFMA16(a[i], b[j], acc[i][j]);
        __syncthreads();
    }
#pragma unroll
    for (int i = 0; i < 4; ++i)
#pragma unroll
    for (int j = 0; j < 4; ++j) {
        int n = n0 + wn * 64 + j * 16 + col;
        int which = n >> 8, h = (n >> 5) & 7, d = n & 31;
        int m = m0 + wm * 64 + i * 16 + q * 4;
        int b = m >> 11, t = m & 2047;
        int bh = b * 8 + h;
        if (which == 0) {
#pragma unroll
            for (int r = 0; r < 4; ++r)
                Qbf[((size_t)bh * TT + t + r) * 32 + d] = f2b(acc[i][j][r] * QSCALE);
        } else if (which == 1) {
#pragma unroll
            for (int r = 0; r < 4; ++r)
                Kbf[((size_t)bh * TT + t + r) * 32 + d] = f2b(acc[i][j][r]);
        } else {
            uint2 pv;
            pv.x = pk_bf16(acc[i][j][0], acc[i][j][1]);
            pv.y = pk_bf16(acc[i][j][2], acc[i][j][3]);
            *(uint2*)&VtRaw[((size_t)bh * 32 + d) * TT + t] = pv;
        }
    }
}

// ---------------------------------------------------------------------------
// Pass 1: colLinv[s] = 1 / sum_{t>=s} exp2(q_t . k_s).
// Block = 4 waves co-owning s-tile pair {u, 63-u}: wave w takes t-chunks
// ct = stile+w, +4, ... ; partial sums combined in LDS. Balanced + 4x waves.
__global__ __launch_bounds__(256, 4) void attn_cols(const unsigned short* __restrict__ Qbf,
                                                    const unsigned short* __restrict__ Kbf,
                                                    float* __restrict__ colLinv) {
    __shared__ float Lb[4][32];
    int tid = threadIdx.x;
    int w = tid >> 6, lane = tid & 63, hi = lane >> 5, l31 = lane & 31;
    int bh = blockIdx.y;
    int u = blockIdx.x;                       // 0..31
    const unsigned short* Qb = Qbf + (size_t)bh * TT * 32;
    const unsigned short* Kb = Kbf + (size_t)bh * TT * 32;
    const f32x16 z16 = {};
#pragma unroll
    for (int phase = 0; phase < 2; ++phase) {
        int stile = phase ? (63 - u) : u;
        int sbase = stile * 32;
        bf16x8 a0 = ld8(Kb + (size_t)(sbase + l31) * 32 + hi * 8);        // d 0..15
        bf16x8 a1 = ld8(Kb + (size_t)(sbase + l31) * 32 + 16 + hi * 8);   // d 16..31
        float acc[16] = {};
        for (int ct = stile + w; ct < 64; ct += 4) {
            int t0 = ct * 32;
            bf16x8 q0 = ld8(Qb + (size_t)(t0 + l31) * 32 + hi * 8);
            bf16x8 q1 = ld8(Qb + (size_t)(t0 + l31) * 32 + 16 + hi * 8);
            f32x16 st = MFMA32(a0, q0, z16);
            st = MFMA32(a1, q1, st);
            if (ct == stile) {
#pragma unroll
                for (int r = 0; r < 16; ++r) {
                    int s_local = (r & 3) + 8 * (r >> 2) + 4 * hi;
                    acc[r] += (l31 >= s_local) ? FEXP2(st[r]) : 0.f;
                }
            } else {
#pragma unroll
                for (int r = 0; r < 16; ++r) acc[r] += FEXP2(st[r]);
            }
        }
#pragma unroll
        for (int off = 1; off <= 16; off <<= 1)
#pragma unroll
            for (int r = 0; r < 16; ++r) acc[r] += __shfl_xor(acc[r], off, 64);
        if (l31 == 0) {
#pragma unroll
            for (int r = 0; r < 16; ++r) {
                int s_local = (r & 3) + 8 * (r >> 2) + 4 * hi;
                Lb[w][s_local] = acc[r];
            }
        }
        __syncthreads();
        if (tid < 32) {
            float s = Lb[0][tid] + Lb[1][tid] + Lb[2][tid] + Lb[3][tid];
            colLinv[(size_t)bh * TT + sbase + tid] = 1.0f / s;
        }
        __syncthreads();
    }
}

// ---------------------------------------------------------------------------
// Vt[bh][d][s] = VtRaw[bh][d][s] * colLinv[bh][s]; one block per (bh,d) row.
__global__ __launch_bounds__(256) void scale_vt(const unsigned short* __restrict__ VtRaw,
                                                const float* __restrict__ colLinv,
                                                unsigned short* __restrict__ Vt) {
    int bhd = blockIdx.x;            // bh*32 + d
    int bh = bhd >> 5;
    int s = threadIdx.x * 8;
    u16x8 v = *(const u16x8*)&VtRaw[(size_t)bhd * TT + s];
    const float4 i0 = *(const float4*)&colLinv[(size_t)bh * TT + s];
    const float4 i1 = *(const float4*)&colLinv[(size_t)bh * TT + s + 4];
    u16x8 o;
    o[0] = f2b(b2f(v[0]) * i0.x); o[1] = f2b(b2f(v[1]) * i0.y);
    o[2] = f2b(b2f(v[2]) * i0.z); o[3] = f2b(b2f(v[3]) * i0.w);
    o[4] = f2b(b2f(v[4]) * i1.x); o[5] = f2b(b2f(v[5]) * i1.y);
    o[6] = f2b(b2f(v[6]) * i1.z); o[7] = f2b(b2f(v[7]) * i1.w);
    *(u16x8*)&Vt[(size_t)bhd * TT + s] = o;
}

// ---------------------------------------------------------------------------
// Pass 2: O[t,:] = sum_{s<=t} exp2(q_t.k_s) * V'[s,:], xh = bf16(xn + O).
// Block = 4 waves co-owning t-tile pair {u, 63-u} (2 phases). Wave w takes
// s-chunks c = w, w+4, ...; partial O combined in LDS (1 barrier/phase).
// Wave-private Pt; S^T=K.Q^T trick (packed b64 LDS writes/reads).
__global__ __launch_bounds__(256, 4) void attn_out(const unsigned short* __restrict__ Qbf,
                                                   const unsigned short* __restrict__ Kbf,
                                                   const unsigned short* __restrict__ Vt,
                                                   const float* __restrict__ xn,
                                                   unsigned short* __restrict__ xh_bf) {
    __shared__ unsigned short Pt[4][32][36];   // 9216 B, wave-private P tiles
    __shared__ float Ob[4][32][36];            // 18432 B, partial-O combine
    int tid = threadIdx.x;
    int w = tid >> 6, lane = tid & 63, q = lane >> 4, col = lane & 15;
    int bh = blockIdx.y, b = bh >> 3, h = bh & 7;
    int u = blockIdx.x;                        // 0..31
    const unsigned short* Kb = Kbf + (size_t)bh * TT * 32;
    const unsigned short* Vb = Vt + (size_t)bh * 32 * TT;
    const f32x4 z = {};

#pragma unroll
    for (int phase = 0; phase < 2; ++phase) {
        int tt = phase ? (63 - u) : u;
        int tbase = tt * 32;
        const unsigned short* Qrow = Qbf + ((size_t)bh * TT + tbase) * 32;
        bf16x8 q0 = ld8(Qrow + (size_t)col * 32 + q * 8);          // t 0..15
        bf16x8 q1 = ld8(Qrow + (size_t)(16 + col) * 32 + q * 8);   // t 16..31
        f32x4 o00 = z, o01 = z, o10 = z, o11 = z;   // [tsub][dsub]

        int c = w;
        bf16x8 ck0 = ld8(Kb + (size_t)(c * 32 + col) * 32 + q * 8);
        bf16x8 ck1 = ld8(Kb + (size_t)(c * 32 + 16 + col) * 32 + q * 8);
        bf16x8 cv0 = ld8(Vb + (size_t)col * TT + c * 32 + q * 8);
        bf16x8 cv1 = ld8(Vb + (size_t)(16 + col) * TT + c * 32 + q * 8);

        for (; c <= tt; c += 4) {
            bool diag = (c == tt);
            // S^T tiles: C-layout col=t_local, row=q*4+r=s_local
            f32x4 st00 = MFMA16(ck0, q0, z);
            f32x4 st01 = MFMA16(ck0, q1, z);
            f32x4 st11 = MFMA16(ck1, q1, z);
            f32x4 st10 = diag ? z : MFMA16(ck1, q0, z);
            // prefetch next chunk (c+4)
            int cn = c + 4;
            if (cn <= tt) {
                ck0 = ld8(Kb + (size_t)(cn * 32 + col) * 32 + q * 8);
                ck1 = ld8(Kb + (size_t)(cn * 32 + 16 + col) * 32 + q * 8);
            }
            uint2 w0, w1, w2, w3;
            if (diag) {   // mask s_g <= t_g
                float e0[4], e1[4], e3[4];
#pragma unroll
                for (int r = 0; r < 4; ++r) {
                    int sl = q * 4 + r;
                    e0[r] = (sl <= col) ? FEXP2(st00[r]) : 0.f;
                    e1[r] = FEXP2(st01[r]);              // s<16<=t: full
                    e3[r] = (sl <= col) ? FEXP2(st11[r]) : 0.f;
                }
                w0.x = pk_bf16(e0[0], e0[1]); w0.y = pk_bf16(e0[2], e0[3]);
                w1.x = pk_bf16(e1[0], e1[1]); w1.y = pk_bf16(e1[2], e1[3]);
                w2.x = 0u;                    w2.y = 0u;
                w3.x = pk_bf16(e3[0], e3[1]); w3.y = pk_bf16(e3[2], e3[3]);
            } else {
                w0.x = pk_bf16(FEXP2(st00[0]), FEXP2(st00[1]));
                w0.y = pk_bf16(FEXP2(st00[2]), FEXP2(st00[3]));
                w1.x = pk_bf16(FEXP2(st01[0]), FEXP2(st01[1]));
                w1.y = pk_bf16(FEXP2(st01[2]), FEXP2(st01[3]));
                w2.x = pk_bf16(FEXP2(st10[0]), FEXP2(st10[1]));
                w2.y = pk_bf16(FEXP2(st10[2]), FEXP2(st10[3]));
                w3.x = pk_bf16(FEXP2(st11[0]), FEXP2(st11[1]));
                w3.y = pk_bf16(FEXP2(st11[2]), FEXP2(st11[3]));
            }
            *(uint2*)&Pt[w][col][q * 4]           = w0;
            *(uint2*)&Pt[w][16 + col][q * 4]      = w1;
            *(uint2*)&Pt[w][col][16 + q * 4]      = w2;
            *(uint2*)&Pt[w][16 + col][16 + q * 4] = w3;
            // P A-frags: two 8B reads each (rows 8B aligned at stride 36)
            union { uint2 u2[2]; bf16x8 v; } p0u, p1u;
            p0u.u2[0] = *(const uint2*)&Pt[w][col][q * 8];
            p0u.u2[1] = *(const uint2*)&Pt[w][col][q * 8 + 4];
            p1u.u2[0] = *(const uint2*)&Pt[w][16 + col][q * 8];
            p1u.u2[1] = *(const uint2*)&Pt[w][16 + col][q * 8 + 4];
            // PV
            o00 = MFMA16(p0u.v, cv0, o00);
            o01 = MFMA16(p0u.v, cv1, o01);
            o10 = MFMA16(p1u.v, cv0, o10);
            o11 = MFMA16(p1u.v, cv1, o11);
            if (cn <= tt) {
                cv0 = ld8(Vb + (size_t)col * TT + cn * 32 + q * 8);
                cv1 = ld8(Vb + (size_t)(16 + col) * TT + cn * 32 + q * 8);
            }
        }

        // Partial-O to LDS (C-layout: row=q*4+r=t_local, col=d_local)
#pragma unroll
        for (int r = 0; r < 4; ++r) {
            Ob[w][q * 4 + r][col]           = o00[r];
            Ob[w][q * 4 + r][16 + col]      = o01[r];
            Ob[w][16 + q * 4 + r][col]      = o10[r];
            Ob[w][16 + q * 4 + r][16 + col] = o11[r];
        }
        __syncthreads();
        // Combine 4 partials + epilogue: 256 thr = 32 rows x 8 col-quads
        {
            int row = tid >> 3;
            int c4 = (tid & 7) * 4;
            float4 s0 = *(const float4*)&Ob[0][row][c4];
            float4 s1 = *(const float4*)&Ob[1][row][c4];
            float4 s2 = *(const float4*)&Ob[2][row][c4];
            float4 s3 = *(const float4*)&Ob[3][row][c4];
            size_t base = ((size_t)(b * TT) + tbase + row) * TE + h * 32 + c4;
            const float4 xv = *(const float4*)&xn[base];
            u16x4 ob = { f2b(s0.x + s1.x + s2.x + s3.x + xv.x),
                         f2b(s0.y + s1.y + s2.y + s3.y + xv.y),
                         f2b(s0.z + s1.z + s2.z + s3.z + xv.z),
                         f2b(s0.w + s1.w + s2.w + s3.w + xv.w) };
            *(u16x4*)&xh_bf[base] = ob;
        }
        __syncthreads();   // Ob reused next phase
    }
}

// ---------------------------------------------------------------------------
extern "C" void kernel_launch(void* const* d_in, const int* in_sizes, int n_in,
                              void* d_out, int out_size, void* d_ws, size_t ws_size,
                              hipStream_t stream) {
    (void)in_sizes; (void)n_in; (void)out_size; (void)ws_size;
    const float* x     = (const float*)d_in[0];
    const float* wq    = (const float*)d_in[1];
    const float* wk    = (const float*)d_in[2];
    const float* wv    = (const float*)d_in[3];
    const float* w_lin = (const float*)d_in[4];
    const float* b_lin = (const float*)d_in[5];
    const float* g1    = (const float*)d_in[6];
    const float* beta1 = (const float*)d_in[7];
    const float* g2    = (const float*)d_in[8];
    const float* beta2 = (const float*)d_in[9];
    const float* w_f1  = (const float*)d_in[10];
    const float* b_f1  = (const float*)d_in[11];
    const float* w_f2  = (const float*)d_in[12];
    const float* b_f2  = (const float*)d_in[13];
    float* out = (float*)d_out;

    char* ws = (char*)d_ws;
    unsigned short* Wqkv_t = (unsigned short*)(ws + 0);         //  384 KB
    unsigned short* Wlin_t = (unsigned short*)(ws + 393216);    //  128 KB
    unsigned short* Wf1_t  = (unsigned short*)(ws + 524288);    //  512 KB
    unsigned short* Wf2_t  = (unsigned short*)(ws + 1048576);   //  512 KB
    float*          xn     = (float*)(ws + 1572864);            //   16 MB  [xl aliases]
    unsigned short* xn_bf  = (unsigned short*)(ws + 18350080);  //    8 MB  [x2_bf aliases]
    unsigned short* Qbf    = (unsigned short*)(ws + 26738688);  //    8 MB ┐
    unsigned short* Kbf    = (unsigned short*)(ws + 35127296);  //    8 MB ├ h_bf aliases (32 MB)
    unsigned short* VtRaw  = (unsigned short*)(ws + 43515904);  //    8 MB │
    unsigned short* Vt     = (unsigned short*)(ws + 51904512);  //    8 MB ┘
    unsigned short* xh_bf  = (unsigned short*)(ws + 60293120);  //    8 MB
    float*          x2     = (float*)(ws + 68681728);           //   16 MB
    float*          colLinv= (float*)(ws + 85459072);           //  512 KB
    float*          xl     = xn;
    unsigned short* x2_bf  = xn_bf;
    unsigned short* h_bf   = Qbf;

    conv_w<<<3072, 256, 0, stream>>>(wq, wk, wv, w_lin, w_f1, w_f2,
                                     Wqkv_t, Wlin_t, Wf1_t, Wf2_t);
    ln_w<<<4096, 256, 0, stream>>>(x, g1, beta1, xn, xn_bf);
    gemm_qkv<<<dim3(128, 6), 256, 0, stream>>>(xn_bf, Wqkv_t, Qbf, Kbf, VtRaw);
    attn_cols<<<dim3(32, 64), 256, 0, stream>>>(Qbf, Kbf, colLinv);
    scale_vt<<<2048, 256, 0, stream>>>(VtRaw, colLinv, Vt);
    attn_out<<<dim3(32, 64), 256, 0, stream>>>(Qbf, Kbf, Vt, xn, xh_bf);
    gemm_lds<256><<<dim3(128, 2), 256, 0, stream>>>(xh_bf, Wlin_t, b_lin, nullptr,
                                                    xl, nullptr, 256, 0);
    ln_w<<<4096, 256, 0, stream>>>(xl, g2, beta2, x2, x2_bf);
    gemm_lds<256><<<dim3(128, 8), 256, 0, stream>>>(x2_bf, Wf1_t, b_f1, nullptr,
                                                    nullptr, h_bf, 1024, 1);
    gemm_lds<1024><<<dim3(128, 2), 256, 0, stream>>>(h_bf, Wf2_t, b_f2, x2,
                                                     out, nullptr, 256, 0);
}

// Round 9
// 282.563 us; speedup vs baseline: 1.6632x; 1.0986x over previous
//
#include <hip/hip_runtime.h>
#include <math.h>

// B=8, T=2048, E=256, H=8, D=32, F=1024
#define TT 2048
#define TE 256
#define NTOK 16384
// Q pre-scale: 256^-0.5 * log2(e)  (so softmax exp == exp2 of scores)
#define QSCALE (0.0625f * 1.44269504088896f)

typedef short  bf16x8 __attribute__((ext_vector_type(8)));
typedef float  f32x4  __attribute__((ext_vector_type(4)));
typedef float  f32x16 __attribute__((ext_vector_type(16)));
typedef unsigned short u16x4 __attribute__((ext_vector_type(4)));
typedef unsigned short u16x8 __attribute__((ext_vector_type(8)));

__device__ __forceinline__ unsigned short f2b(float f) {
    union { float f; unsigned int u; } v; v.f = f;
    unsigned int r = v.u + 0x7FFF + ((v.u >> 16) & 1);   // RNE
    return (unsigned short)(r >> 16);
}
__device__ __forceinline__ float b2f(unsigned short u) {
    union { unsigned int i; float f; } v; v.i = ((unsigned int)u) << 16;
    return v.f;
}
#if __has_builtin(__builtin_amdgcn_cvt_pk_bf16_f32)
__device__ __forceinline__ unsigned int pk_bf16(float a, float b) {
    typedef __bf16 bf2 __attribute__((ext_vector_type(2)));
    union { bf2 v; unsigned int u; } u;
    u.v = __builtin_amdgcn_cvt_pk_bf16_f32(a, b);
    return u.u;
}
#else
__device__ __forceinline__ unsigned int pk_bf16(float a, float b) {
    return (unsigned int)f2b(a) | ((unsigned int)f2b(b) << 16);
}
#endif
// Native exp2 (single v_exp_f32) — exp2f w/o fast-math is the slow OCML path.
#if __has_builtin(__builtin_amdgcn_exp2f)
#define FEXP2(x) __builtin_amdgcn_exp2f(x)
#else
#define FEXP2(x) __expf(0.69314718056f * (x))
#endif
__device__ __forceinline__ bf16x8 ld8(const unsigned short* p) {
    return *(const bf16x8*)p;
}
// Async global->LDS, 16B/lane. LDS dest = wave-uniform base + lane*16.
__device__ __forceinline__ void gl_lds16(const unsigned short* g, unsigned short* l) {
    __builtin_amdgcn_global_load_lds(
        (const __attribute__((address_space(1))) unsigned int*)(uintptr_t)g,
        (__attribute__((address_space(3))) unsigned int*)(uintptr_t)l,
        16, 0, 0);
}
#define MFMA16(a, b, c) __builtin_amdgcn_mfma_f32_16x16x32_bf16((a), (b), (c), 0, 0, 0)
#define MFMA32(a, b, c) __builtin_amdgcn_mfma_f32_32x32x16_bf16((a), (b), (c), 0, 0, 0)

// ---------------------------------------------------------------------------
// Weight convert/transpose to bf16 [N][K] row-major
__global__ __launch_bounds__(256) void conv_w(const float* __restrict__ wq,
                                              const float* __restrict__ wk,
                                              const float* __restrict__ wv,
                                              const float* __restrict__ w_lin,
                                              const float* __restrict__ w_f1,
                                              const float* __restrict__ w_f2,
                                              unsigned short* __restrict__ Wqkv,
                                              unsigned short* __restrict__ Wlin,
                                              unsigned short* __restrict__ Wf1,
                                              unsigned short* __restrict__ Wf2) {
    int idx = blockIdx.x * 256 + threadIdx.x;
    if (idx < 196608) {                       // Wqkv_t [768][256]
        int n = idx >> 8, k = idx & 255;
        int which = n >> 8, h = (n >> 5) & 7, d = n & 31;
        const float* w = (which == 0) ? wq : (which == 1) ? wk : wv;
        Wqkv[idx] = f2b(w[(h * 256 + k) * 32 + d]);
    } else if (idx < 262144) {                // Wlin_t [256][256]
        int i = idx - 196608; int n = i >> 8, k = i & 255;
        Wlin[i] = f2b(w_lin[k * 256 + n]);
    } else if (idx < 524288) {                // Wf1_t [1024][256]
        int i = idx - 262144; int n = i >> 8, k = i & 255;
        Wf1[i] = f2b(w_f1[k * 1024 + n]);
    } else {                                  // Wf2_t [256][1024]
        int i = idx - 524288; int n = i >> 10, k = i & 1023;
        Wf2[i] = f2b(w_f2[k * 256 + n]);
    }
}

// ---------------------------------------------------------------------------
// LayerNorm, wave-per-row, shuffle reduce; bf16 (and optional fp32) outputs.
__global__ __launch_bounds__(256) void ln_w(const float* __restrict__ X,
                                            const float* __restrict__ g,
                                            const float* __restrict__ bta,
                                            float* __restrict__ Y,
                                            unsigned short* __restrict__ Yb) {
    int row = blockIdx.x * 4 + (threadIdx.x >> 6);
    int lane = threadIdx.x & 63;
    const float4 v = *(const float4*)&X[(size_t)row * TE + lane * 4];
    float s = v.x + v.y + v.z + v.w;
    float s2 = v.x * v.x + v.y * v.y + v.z * v.z + v.w * v.w;
#pragma unroll
    for (int off = 1; off <= 32; off <<= 1) {
        s  += __shfl_xor(s,  off, 64);
        s2 += __shfl_xor(s2, off, 64);
    }
    float mean = s * (1.0f / TE);
    float var = s2 * (1.0f / TE) - mean * mean;
    float rstd = rsqrtf(var + 1e-5f);
    const float4 gg = *(const float4*)&g[lane * 4];
    const float4 bb = *(const float4*)&bta[lane * 4];
    float4 o;
    o.x = (v.x - mean) * rstd * gg.x + bb.x;
    o.y = (v.y - mean) * rstd * gg.y + bb.y;
    o.z = (v.z - mean) * rstd * gg.z + bb.z;
    o.w = (v.w - mean) * rstd * gg.w + bb.w;
    if (Y) *(float4*)&Y[(size_t)row * TE + lane * 4] = o;
    if (Yb) {
        u16x4 ob = { f2b(o.x), f2b(o.y), f2b(o.z), f2b(o.w) };
        *(u16x4*)&Yb[(size_t)row * TE + lane * 4] = ob;
    }
}

// ---------------------------------------------------------------------------
// Fused proj-reduce + LayerNorm2: xl = Pp0 + Pp1 + b_lin; x2 = LN(xl) -> bf16
__global__ __launch_bounds__(256) void ln2_red(const float* __restrict__ Pp,
                                               const float* __restrict__ bias,
                                               const float* __restrict__ g,
                                               const float* __restrict__ bta,
                                               unsigned short* __restrict__ Yb) {
    const size_t SL = (size_t)NTOK * TE;
    int row = blockIdx.x * 4 + (threadIdx.x >> 6);
    int lane = threadIdx.x & 63;
    size_t base = (size_t)row * TE + lane * 4;
    const float4 p0 = *(const float4*)&Pp[base];
    const float4 p1 = *(const float4*)&Pp[SL + base];
    const float4 bl = *(const float4*)&bias[lane * 4];
    float4 v;
    v.x = p0.x + p1.x + bl.x; v.y = p0.y + p1.y + bl.y;
    v.z = p0.z + p1.z + bl.z; v.w = p0.w + p1.w + bl.w;
    float s = v.x + v.y + v.z + v.w;
    float s2 = v.x * v.x + v.y * v.y + v.z * v.z + v.w * v.w;
#pragma unroll
    for (int off = 1; off <= 32; off <<= 1) {
        s  += __shfl_xor(s,  off, 64);
        s2 += __shfl_xor(s2, off, 64);
    }
    float mean = s * (1.0f / TE);
    float var = s2 * (1.0f / TE) - mean * mean;
    float rstd = rsqrtf(var + 1e-5f);
    const float4 gg = *(const float4*)&g[lane * 4];
    const float4 bb = *(const float4*)&bta[lane * 4];
    u16x4 ob = { f2b((v.x - mean) * rstd * gg.x + bb.x),
                 f2b((v.y - mean) * rstd * gg.y + bb.y),
                 f2b((v.z - mean) * rstd * gg.z + bb.z),
                 f2b((v.w - mean) * rstd * gg.w + bb.w) };
    *(u16x4*)&Yb[base] = ob;
}

// ---------------------------------------------------------------------------
// FFN2 reduce: out = sum_z Pf[z] + b_f2 + x2   (Pf bf16, x2 bf16, out fp32)
__global__ __launch_bounds__(256) void reduce2(const unsigned short* __restrict__ Pf,
                                               const float* __restrict__ bias,
                                               const unsigned short* __restrict__ x2b,
                                               float* __restrict__ out) {
    const size_t SL = (size_t)NTOK * TE;
    int row = blockIdx.x * 4 + (threadIdx.x >> 6);
    int lane = threadIdx.x & 63;
    size_t base = (size_t)row * TE + lane * 4;
    const float4 bl = *(const float4*)&bias[lane * 4];
    u16x4 r = *(const u16x4*)&x2b[base];
    float4 acc;
    acc.x = bl.x + b2f(r[0]); acc.y = bl.y + b2f(r[1]);
    acc.z = bl.z + b2f(r[2]); acc.w = bl.w + b2f(r[3]);
#pragma unroll
    for (int z = 0; z < 4; ++z) {
        u16x4 p = *(const u16x4*)&Pf[z * SL + base];
        acc.x += b2f(p[0]); acc.y += b2f(p[1]);
        acc.z += b2f(p[2]); acc.w += b2f(p[3]);
    }
    *(float4*)&out[base] = acc;
}

// ---------------------------------------------------------------------------
// LDS-staged bf16 MFMA GEMM with split-K: C_z[M,N] = A[:, zKS:(z+1)KS] @ ...
// Block 128x128 (2x2 waves, 64x64 wave tile), BK=32, global_load_lds w=16.
// Grid (m-tiles, n-tiles, z). Output offset z*16384*N (partial buffers).
template<int KS>
__global__ __launch_bounds__(256) void gemm_lds(const unsigned short* __restrict__ A,
                                                int lda,
                                                const unsigned short* __restrict__ Bt,
                                                int ldb,
                                                const float* __restrict__ bias,
                                                float* __restrict__ outF,
                                                unsigned short* __restrict__ outB,
                                                int N, int relu) {
    __shared__ unsigned short Al[128 * 32];
    __shared__ unsigned short Bl[128 * 32];
    int tid = threadIdx.x;
    int w = tid >> 6, lane = tid & 63, q = lane >> 4, col = lane & 15;
    int wm = w & 1, wn = w >> 1;
    int m0 = blockIdx.x * 128;
    int n0 = blockIdx.y * 128;
    int koff = blockIdx.z * KS;
    size_t zoff = (size_t)blockIdx.z * NTOK * N;
    f32x4 acc[4][4] = {};
    // Staging: wave w owns rows [32w, 32w+32) of both tiles, 2 instrs each.
    int srow = lane >> 2;            // 0..15
    int skq  = (lane & 3) * 8;       // k elem offset {0,8,16,24} (16B)
    const unsigned short* Ag0 = A  + (size_t)(m0 + w * 32 + srow) * lda + koff + skq;
    const unsigned short* Ag1 = Ag0 + (size_t)16 * lda;
    const unsigned short* Bg0 = Bt + (size_t)(n0 + w * 32 + srow) * ldb + koff + skq;
    const unsigned short* Bg1 = Bg0 + (size_t)16 * ldb;
    unsigned short* Asl0 = &Al[(w * 32) * 32];
    unsigned short* Asl1 = Asl0 + 16 * 32;
    unsigned short* Bsl0 = &Bl[(w * 32) * 32];
    unsigned short* Bsl1 = Bsl0 + 16 * 32;
    for (int k0 = 0; k0 < KS; k0 += 32) {
        gl_lds16(Ag0 + k0, Asl0);
        gl_lds16(Ag1 + k0, Asl1);
        gl_lds16(Bg0 + k0, Bsl0);
        gl_lds16(Bg1 + k0, Bsl1);
        __syncthreads();
        bf16x8 a[4], b[4];
#pragma unroll
        for (int i = 0; i < 4; ++i)
            a[i] = ld8(&Al[(wm * 64 + i * 16 + col) * 32 + q * 8]);
#pragma unroll
        for (int j = 0; j < 4; ++j)
            b[j] = ld8(&Bl[(wn * 64 + j * 16 + col) * 32 + q * 8]);
#pragma unroll
        for (int i = 0; i < 4; ++i)
#pragma unroll
            for (int j = 0; j < 4; ++j)
                acc[i][j] = MFMA16(a[i], b[j], acc[i][j]);
        __syncthreads();
    }
#pragma unroll
    for (int i = 0; i < 4; ++i)
#pragma unroll
    for (int j = 0; j < 4; ++j) {
        int n = n0 + wn * 64 + j * 16 + col;
#pragma unroll
        for (int r = 0; r < 4; ++r) {
            int m = m0 + wm * 64 + i * 16 + q * 4 + r;
            float v = acc[i][j][r];
            if (bias) v += bias[n];
            if (relu) v = fmaxf(v, 0.f);
            if (outF) outF[zoff + (size_t)m * N + n] = v;
            if (outB) outB[zoff + (size_t)m * N + n] = f2b(v);
        }
    }
}

// ---------------------------------------------------------------------------
// QKV GEMM, same staged core (K=256). Epilogue scatter: Qbf (x QSCALE), Kbf
// in [bh][t][32]; V^T (unscaled bf16) in [bh][d][TT], packed uint2 stores.
__global__ __launch_bounds__(256) void gemm_qkv(const unsigned short* __restrict__ A,
                                                const unsigned short* __restrict__ Bt,
                                                unsigned short* __restrict__ Qbf,
                                                unsigned short* __restrict__ Kbf,
                                                unsigned short* __restrict__ VtRaw) {
    const int K = 256;
    __shared__ unsigned short Al[128 * 32];
    __shared__ unsigned short Bl[128 * 32];
    int tid = threadIdx.x;
    int w = tid >> 6, lane = tid & 63, q = lane >> 4, col = lane & 15;
    int wm = w & 1, wn = w >> 1;
    int m0 = blockIdx.x * 128;
    int n0 = blockIdx.y * 128;
    f32x4 acc[4][4] = {};
    int srow = lane >> 2;
    int skq  = (lane & 3) * 8;
    const unsigned short* Ag0 = A  + (size_t)(m0 + w * 32 + srow) * K + skq;
    const unsigned short* Ag1 = Ag0 + (size_t)16 * K;
    const unsigned short* Bg0 = Bt + (size_t)(n0 + w * 32 + srow) * K + skq;
    const unsigned short* Bg1 = Bg0 + (size_t)16 * K;
    unsigned short* Asl0 = &Al[(w * 32) * 32];
    unsigned short* Asl1 = Asl0 + 16 * 32;
    unsigned short* Bsl0 = &Bl[(w * 32) * 32];
    unsigned short* Bsl1 = Bsl0 + 16 * 32;
    for (int k0 = 0; k0 < K; k0 += 32) {
        gl_lds16(Ag0 + k0, Asl0);
        gl_lds16(Ag1 + k0, Asl1);
        gl_lds16(Bg0 + k0, Bsl0);
        gl_lds16(Bg1 + k0, Bsl1);
        __syncthreads();
        bf16x8 a[4], b[4];
#pragma unroll
        for (int i = 0; i < 4; ++i)
            a[i] = ld8(&Al[(wm * 64 + i * 16 + col) * 32 + q * 8]);
#pragma unroll
        for (int j = 0; j < 4; ++j)
            b[j] = ld8(&Bl[(wn * 64 + j * 16 + col) * 32 + q * 8]);
#pragma unroll
        for (int i = 0; i < 4; ++i)
#pragma unroll
            for (int j = 0; j < 4; ++j)
                acc[i][j] = MFMA16(a[i], b[j], acc[i][j]);
        __syncthreads();
    }
#pragma unroll
    for (int i = 0; i < 4; ++i)
#pragma unroll
    for (int j = 0; j < 4; ++j) {
        int n = n0 + wn * 64 + j * 16 + col;
        int which = n >> 8, h = (n >> 5) & 7, d = n & 31;
        int m = m0 + wm * 64 + i * 16 + q * 4;
        int b = m >> 11, t = m & 2047;
        int bh = b * 8 + h;
        if (which == 0) {
#pragma unroll
            for (int r = 0; r < 4; ++r)
                Qbf[((size_t)bh * TT + t + r) * 32 + d] = f2b(acc[i][j][r] * QSCALE);
        } else if (which == 1) {
#pragma unroll
            for (int r = 0; r < 4; ++r)
                Kbf[((size_t)bh * TT + t + r) * 32 + d] = f2b(acc[i][j][r]);
        } else {
            uint2 pv;
            pv.x = pk_bf16(acc[i][j][0], acc[i][j][1]);
            pv.y = pk_bf16(acc[i][j][2], acc[i][j][3]);
            *(uint2*)&VtRaw[((size_t)bh * 32 + d) * TT + t] = pv;
        }
    }
}

// ---------------------------------------------------------------------------
// Pass 1: colLinv[s] = 1 / sum_{t>=s} exp2(q_t . k_s).
// Grid (bh, u): same-bh blocks 64 apart -> same XCD -> K/Q stay L2-resident.
__global__ __launch_bounds__(256, 4) void attn_cols(const unsigned short* __restrict__ Qbf,
                                                    const unsigned short* __restrict__ Kbf,
                                                    float* __restrict__ colLinv) {
    __shared__ float Lb[4][32];
    int tid = threadIdx.x;
    int w = tid >> 6, lane = tid & 63, hi = lane >> 5, l31 = lane & 31;
    int bh = blockIdx.x;
    int u = blockIdx.y;                       // 0..31
    const unsigned short* Qb = Qbf + (size_t)bh * TT * 32;
    const unsigned short* Kb = Kbf + (size_t)bh * TT * 32;
    const f32x16 z16 = {};
#pragma unroll
    for (int phase = 0; phase < 2; ++phase) {
        int stile = phase ? (63 - u) : u;
        int sbase = stile * 32;
        bf16x8 a0 = ld8(Kb + (size_t)(sbase + l31) * 32 + hi * 8);        // d 0..15
        bf16x8 a1 = ld8(Kb + (size_t)(sbase + l31) * 32 + 16 + hi * 8);   // d 16..31
        float acc[16] = {};
        for (int ct = stile + w; ct < 64; ct += 4) {
            int t0 = ct * 32;
            bf16x8 q0 = ld8(Qb + (size_t)(t0 + l31) * 32 + hi * 8);
            bf16x8 q1 = ld8(Qb + (size_t)(t0 + l31) * 32 + 16 + hi * 8);
            f32x16 st = MFMA32(a0, q0, z16);
            st = MFMA32(a1, q1, st);
            if (ct == stile) {
#pragma unroll
                for (int r = 0; r < 16; ++r) {
                    int s_local = (r & 3) + 8 * (r >> 2) + 4 * hi;
                    acc[r] += (l31 >= s_local) ? FEXP2(st[r]) : 0.f;
                }
            } else {
#pragma unroll
                for (int r = 0; r < 16; ++r) acc[r] += FEXP2(st[r]);
            }
        }
#pragma unroll
        for (int off = 1; off <= 16; off <<= 1)
#pragma unroll
            for (int r = 0; r < 16; ++r) acc[r] += __shfl_xor(acc[r], off, 64);
        if (l31 == 0) {
#pragma unroll
            for (int r = 0; r < 16; ++r) {
                int s_local = (r & 3) + 8 * (r >> 2) + 4 * hi;
                Lb[w][s_local] = acc[r];
            }
        }
        __syncthreads();
        if (tid < 32) {
            float s = Lb[0][tid] + Lb[1][tid] + Lb[2][tid] + Lb[3][tid];
            colLinv[(size_t)bh * TT + sbase + tid] = 1.0f / s;
        }
        __syncthreads();
    }
}

// ---------------------------------------------------------------------------
// Vt[bh][d][s] *= colLinv[bh][s]  (in-place; each elem read+written once)
__global__ __launch_bounds__(256) void scale_vt(unsigned short* __restrict__ Vt,
                                                const float* __restrict__ colLinv) {
    int bhd = blockIdx.x;            // bh*32 + d
    int bh = bhd >> 5;
    int s = threadIdx.x * 8;
    u16x8 v = *(const u16x8*)&Vt[(size_t)bhd * TT + s];
    const float4 i0 = *(const float4*)&colLinv[(size_t)bh * TT + s];
    const float4 i1 = *(const float4*)&colLinv[(size_t)bh * TT + s + 4];
    u16x8 o;
    o[0] = f2b(b2f(v[0]) * i0.x); o[1] = f2b(b2f(v[1]) * i0.y);
    o[2] = f2b(b2f(v[2]) * i0.z); o[3] = f2b(b2f(v[3]) * i0.w);
    o[4] = f2b(b2f(v[4]) * i1.x); o[5] = f2b(b2f(v[5]) * i1.y);
    o[6] = f2b(b2f(v[6]) * i1.z); o[7] = f2b(b2f(v[7]) * i1.w);
    *(u16x8*)&Vt[(size_t)bhd * TT + s] = o;
}

// ---------------------------------------------------------------------------
// Pass 2: O[t,:] = sum_{s<=t} exp2(q_t.k_s) * V'[s,:], xh = bf16(xn + O).
// Grid (bh, u): same-bh blocks on same XCD (L2 reuse). 4 waves co-own the
// t-tile pair {u, 63-u}; wave w takes s-chunks c=w, w+4, ...; partial O
// combined in LDS. Wave-private Pt; S^T=K.Q^T trick.
__global__ __launch_bounds__(256, 4) void attn_out(const unsigned short* __restrict__ Qbf,
                                                   const unsigned short* __restrict__ Kbf,
                                                   const unsigned short* __restrict__ Vt,
                                                   const unsigned short* __restrict__ xnb,
                                                   unsigned short* __restrict__ xh_bf) {
    __shared__ unsigned short Pt[4][32][36];   // 9216 B, wave-private P tiles
    __shared__ float Ob[4][32][36];            // 18432 B, partial-O combine
    int tid = threadIdx.x;
    int w = tid >> 6, lane = tid & 63, q = lane >> 4, col = lane & 15;
    int bh = blockIdx.x, b = bh >> 3, h = bh & 7;
    int u = blockIdx.y;                        // 0..31
    const unsigned short* Kb = Kbf + (size_t)bh * TT * 32;
    const unsigned short* Vb = Vt + (size_t)bh * 32 * TT;
    const f32x4 z = {};

#pragma unroll
    for (int phase = 0; phase < 2; ++phase) {
        int tt = phase ? (63 - u) : u;
        int tbase = tt * 32;
        const unsigned short* Qrow = Qbf + ((size_t)bh * TT + tbase) * 32;
        bf16x8 q0 = ld8(Qrow + (size_t)col * 32 + q * 8);          // t 0..15
        bf16x8 q1 = ld8(Qrow + (size_t)(16 + col) * 32 + q * 8);   // t 16..31
        f32x4 o00 = z, o01 = z, o10 = z, o11 = z;   // [tsub][dsub]

        int c = w;
        bf16x8 ck0 = ld8(Kb + (size_t)(c * 32 + col) * 32 + q * 8);
        bf16x8 ck1 = ld8(Kb + (size_t)(c * 32 + 16 + col) * 32 + q * 8);
        bf16x8 cv0 = ld8(Vb + (size_t)col * TT + c * 32 + q * 8);
        bf16x8 cv1 = ld8(Vb + (size_t)(16 + col) * TT + c * 32 + q * 8);

        for (; c <= tt; c += 4) {
            bool diag = (c == tt);
            // S^T tiles: C-layout col=t_local, row=q*4+r=s_local
            f32x4 st00 = MFMA16(ck0, q0, z);
            f32x4 st01 = MFMA16(ck0, q1, z);
            f32x4 st11 = MFMA16(ck1, q1, z);
            f32x4 st10 = diag ? z : MFMA16(ck1, q0, z);
            // prefetch next chunk (c+4)
            int cn = c + 4;
            if (cn <= tt) {
                ck0 = ld8(Kb + (size_t)(cn * 32 + col) * 32 + q * 8);
                ck1 = ld8(Kb + (size_t)(cn * 32 + 16 + col) * 32 + q * 8);
            }
            uint2 w0, w1, w2, w3;
            if (diag) {   // mask s_g <= t_g
                float e0[4], e1[4], e3[4];
#pragma unroll
                for (int r = 0; r < 4; ++r) {
                    int sl = q * 4 + r;
                    e0[r] = (sl <= col) ? FEXP2(st00[r]) : 0.f;
                    e1[r] = FEXP2(st01[r]);              // s<16<=t: full
                    e3[r] = (sl <= col) ? FEXP2(st11[r]) : 0.f;
                }
                w0.x = pk_bf16(e0[0], e0[1]); w0.y = pk_bf16(e0[2], e0[3]);
                w1.x = pk_bf16(e1[0], e1[1]); w1.y = pk_bf16(e1[2], e1[3]);
                w2.x = 0u;                    w2.y = 0u;
                w3.x = pk_bf16(e3[0], e3[1]); w3.y = pk_bf16(e3[2], e3[3]);
            } else {
                w0.x = pk_bf16(FEXP2(st00[0]), FEXP2(st00[1]));
                w0.y = pk_bf16(FEXP2(st00[2]), FEXP2(st00[3]));
                w1.x = pk_bf16(FEXP2(st01[0]), FEXP2(st01[1]));
                w1.y = pk_bf16(FEXP2(st01[2]), FEXP2(st01[3]));
                w2.x = pk_bf16(FEXP2(st10[0]), FEXP2(st10[1]));
                w2.y = pk_bf16(FEXP2(st10[2]), FEXP2(st10[3]));
                w3.x = pk_bf16(FEXP2(st11[0]), FEXP2(st11[1]));
                w3.y = pk_bf16(FEXP2(st11[2]), FEXP2(st11[3]));
            }
            *(uint2*)&Pt[w][col][q * 4]           = w0;
            *(uint2*)&Pt[w][16 + col][q * 4]      = w1;
            *(uint2*)&Pt[w][col][16 + q * 4]      = w2;
            *(uint2*)&Pt[w][16 + col][16 + q * 4] = w3;
            // P A-frags: two 8B reads each (rows 8B aligned at stride 36)
            union { uint2 u2[2]; bf16x8 v; } p0u, p1u;
            p0u.u2[0] = *(const uint2*)&Pt[w][col][q * 8];
            p0u.u2[1] = *(const uint2*)&Pt[w][col][q * 8 + 4];
            p1u.u2[0] = *(const uint2*)&Pt[w][16 + col][q * 8];
            p1u.u2[1] = *(const uint2*)&Pt[w][16 + col][q * 8 + 4];
            // PV
            o00 = MFMA16(p0u.v, cv0, o00);
            o01 = MFMA16(p0u.v, cv1, o01);
            o10 = MFMA16(p1u.v, cv0, o10);
            o11 = MFMA16(p1u.v, cv1, o11);
            if (cn <= tt) {
                cv0 = ld8(Vb + (size_t)col * TT + cn * 32 + q * 8);
                cv1 = ld8(Vb + (size_t)(16 + col) * TT + cn * 32 + q * 8);
            }
        }

        // Partial-O to LDS (C-layout: row=q*4+r=t_local, col=d_local)
#pragma unroll
        for (int r = 0; r < 4; ++r) {
            Ob[w][q * 4 + r][col]           = o00[r];
            Ob[w][q * 4 + r][16 + col]      = o01[r];
            Ob[w][16 + q * 4 + r][col]      = o10[r];
            Ob[w][16 + q * 4 + r][16 + col] = o11[r];
        }
        __syncthreads();
        // Combine 4 partials + epilogue: 256 thr = 32 rows x 8 col-quads
        {
            int row = tid >> 3;
            int c4 = (tid & 7) * 4;
            float4 s0 = *(const float4*)&Ob[0][row][c4];
            float4 s1 = *(const float4*)&Ob[1][row][c4];
            float4 s2 = *(const float4*)&Ob[2][row][c4];
            float4 s3 = *(const float4*)&Ob[3][row][c4];
            size_t base = ((size_t)(b * TT) + tbase + row) * TE + h * 32 + c4;
            u16x4 xv = *(const u16x4*)&xnb[base];
            u16x4 ob = { f2b(s0.x + s1.x + s2.x + s3.x + b2f(xv[0])),
                         f2b(s0.y + s1.y + s2.y + s3.y + b2f(xv[1])),
                         f2b(s0.z + s1.z + s2.z + s3.z + b2f(xv[2])),
                         f2b(s0.w + s1.w + s2.w + s3.w + b2f(xv[3])) };
            *(u16x4*)&xh_bf[base] = ob;
        }
        __syncthreads();   // Ob reused next phase
    }
}

// ---------------------------------------------------------------------------
extern "C" void kernel_launch(void* const* d_in, const int* in_sizes, int n_in,
                              void* d_out, int out_size, void* d_ws, size_t ws_size,
                              hipStream_t stream) {
    (void)in_sizes; (void)n_in; (void)out_size; (void)ws_size;
    const float* x     = (const float*)d_in[0];
    const float* wq    = (const float*)d_in[1];
    const float* wk    = (const float*)d_in[2];
    const float* wv    = (const float*)d_in[3];
    const float* w_lin = (const float*)d_in[4];
    const float* b_lin = (const float*)d_in[5];
    const float* g1    = (const float*)d_in[6];
    const float* beta1 = (const float*)d_in[7];
    const float* g2    = (const float*)d_in[8];
    const float* beta2 = (const float*)d_in[9];
    const float* w_f1  = (const float*)d_in[10];
    const float* b_f1  = (const float*)d_in[11];
    const float* w_f2  = (const float*)d_in[12];
    const float* b_f2  = (const float*)d_in[13];
    float* out = (float*)d_out;

    // Workspace layout (bytes), max 74 MB:
    char* ws = (char*)d_ws;
    unsigned short* Wqkv_t = (unsigned short*)(ws + 0);         //  384 KB
    unsigned short* Wlin_t = (unsigned short*)(ws + 393216);    //  128 KB
    unsigned short* Wf1_t  = (unsigned short*)(ws + 524288);    //  512 KB
    unsigned short* Wf2_t  = (unsigned short*)(ws + 1048576);   //  512 KB
    float*          colLinv= (float*)(ws + 1572864);            //  512 KB
    unsigned short* xn_bf  = (unsigned short*)(ws + 2097152);   //    8 MB [x2_bf aliases]
    unsigned short* Qbf    = (unsigned short*)(ws + 10485760);  //    8 MB ┐
    unsigned short* Kbf    = (unsigned short*)(ws + 18874368);  //    8 MB ├ h_bf (32 MB) aliases
    unsigned short* Vt     = (unsigned short*)(ws + 27262976);  //    8 MB │ (in-place scale)
    unsigned short* xh_bf  = (unsigned short*)(ws + 35651584);  //    8 MB ┘
    float*          Pp     = (float*)(ws + 44040192);           //   32 MB proj partials (fp32 x2)
    unsigned short* Pf     = (unsigned short*)(ws + 44040192);  //   32 MB ffn2 partials (bf16 x4)
    unsigned short* x2_bf  = xn_bf;
    unsigned short* h_bf   = Qbf;   // 32 MB spanning Qbf..xh_bf (dead by FFN1)

    conv_w<<<3072, 256, 0, stream>>>(wq, wk, wv, w_lin, w_f1, w_f2,
                                     Wqkv_t, Wlin_t, Wf1_t, Wf2_t);
    ln_w<<<4096, 256, 0, stream>>>(x, g1, beta1, nullptr, xn_bf);
    gemm_qkv<<<dim3(128, 6), 256, 0, stream>>>(xn_bf, Wqkv_t, Qbf, Kbf, Vt);
    attn_cols<<<dim3(64, 32), 256, 0, stream>>>(Qbf, Kbf, colLinv);
    scale_vt<<<2048, 256, 0, stream>>>(Vt, colLinv);
    attn_out<<<dim3(64, 32), 256, 0, stream>>>(Qbf, Kbf, Vt, xn_bf, xh_bf);
    // proj: split-K=2 (K=256 -> 2x128), fp32 partials, bias folded into ln2
    gemm_lds<128><<<dim3(128, 2, 2), 256, 0, stream>>>(xh_bf, 256, Wlin_t, 256,
                                                       nullptr, Pp, nullptr, 256, 0);
    ln2_red<<<4096, 256, 0, stream>>>(Pp, b_lin, g2, beta2, x2_bf);
    gemm_lds<256><<<dim3(128, 8, 1), 256, 0, stream>>>(x2_bf, 256, Wf1_t, 256,
                                                       b_f1, nullptr, h_bf, 1024, 1);
    // ffn2: split-K=4 (K=1024 -> 4x256), bf16 partials
    gemm_lds<256><<<dim3(128, 2, 4), 256, 0, stream>>>(h_bf, 1024, Wf2_t, 1024,
                                                       nullptr, nullptr, Pf, 256, 0);
    reduce2<<<4096, 256, 0, stream>>>(Pf, b_f2, x2_bf, out);
}